// Round 1
// baseline (12404.380 us; speedup 1.0000x reference)
//
#include <hip/hip_runtime.h>

typedef _Float16 f16;
typedef f16 half8 __attribute__((ext_vector_type(8)));
typedef float f32x4 __attribute__((ext_vector_type(4)));

constexpr int HID = 1024;
constexpr int NBAT = 128;
constexpr int SEQ = 256;
constexpr int NBL = 64;    // blocks per layer
constexpr int UPB = 16;    // hidden units per block
constexpr int AST = 2048;  // h-buffer row stride ([h0 | h1])

__device__ __forceinline__ float sigm(float x) { return 1.0f / (1.0f + __expf(-x)); }
__device__ __forceinline__ float tanh_(float x) {
  float e = __expf(2.0f * x);
  return (e - 1.0f) / (e + 1.0f);
}

#define MFMA8(s)                                                               \
  acc00 = __builtin_amdgcn_mfma_f32_16x16x32_f16(a0_##s, b0_##s, acc00, 0, 0, 0); \
  acc01 = __builtin_amdgcn_mfma_f32_16x16x32_f16(a0_##s, b1_##s, acc01, 0, 0, 0); \
  acc02 = __builtin_amdgcn_mfma_f32_16x16x32_f16(a0_##s, b2_##s, acc02, 0, 0, 0); \
  acc03 = __builtin_amdgcn_mfma_f32_16x16x32_f16(a0_##s, b3_##s, acc03, 0, 0, 0); \
  acc10 = __builtin_amdgcn_mfma_f32_16x16x32_f16(a1_##s, b0_##s, acc10, 0, 0, 0); \
  acc11 = __builtin_amdgcn_mfma_f32_16x16x32_f16(a1_##s, b1_##s, acc11, 0, 0, 0); \
  acc12 = __builtin_amdgcn_mfma_f32_16x16x32_f16(a1_##s, b2_##s, acc12, 0, 0, 0); \
  acc13 = __builtin_amdgcn_mfma_f32_16x16x32_f16(a1_##s, b3_##s, acc13, 0, 0, 0);

#define LOADF(s, ks)                                                           \
  a0_##s = *(const half8*)(A0 + (ks) * 32);                                    \
  a1_##s = *(const half8*)(A1 + (ks) * 32);                                    \
  b0_##s = *(const half8*)(W0 + (ks) * 32);                                    \
  b1_##s = *(const half8*)(W1 + (ks) * 32);                                    \
  b2_##s = *(const half8*)(W2 + (ks) * 32);                                    \
  b3_##s = *(const half8*)(W3 + (ks) * 32);

// One block computes gates[0:128, 4 gates x 16 units] for its unit slice,
// then the LSTM elementwise. D-frag mapping (m89): col = lane&15 (unit),
// row = (lane>>4)*4 + reg (batch). A-frag: row = lane&15, k = (lane>>4)*8.
template <int KSTEPS, bool L0>
__device__ void lstm_tile(const f16* __restrict__ A,   // read buffer [128][2048]
                          f16* __restrict__ Hout,      // write buffer base + col offset
                          const f16* __restrict__ W,   // [4096][K]
                          const float* __restrict__ bias,
                          float* __restrict__ C,       // [128][1024]
                          const float* __restrict__ xcol,  // L0: X + (t-1)
                          const float* __restrict__ wih0,  // L0: [4096]
                          const float* __restrict__ wlin,  // L1: [1024]
                          float* __restrict__ ypt,         // L1: yp + (t-2)*128*64
                          int ublk) {
  constexpr int K = KSTEPS * 32;
  const int tid = threadIdx.x;
  const int w = tid >> 6;
  const int l = tid & 63;
  const int l15 = l & 15, lhi = l >> 4;
  const int u0 = ublk * UPB;
  const int m = u0 + l15;  // this lane's hidden unit

  const f16* A0 = A + (size_t)(32 * w + l15) * AST + lhi * 8;
  const f16* A1 = A0 + (size_t)16 * AST;
  const f16* W0 = W + (size_t)(0 * HID + m) * K + lhi * 8;
  const f16* W1 = W + (size_t)(1 * HID + m) * K + lhi * 8;
  const f16* W2 = W + (size_t)(2 * HID + m) * K + lhi * 8;
  const f16* W3 = W + (size_t)(3 * HID + m) * K + lhi * 8;

  f32x4 acc00{}, acc01{}, acc02{}, acc03{}, acc10{}, acc11{}, acc12{}, acc13{};

  half8 a0_0, a1_0, b0_0, b1_0, b2_0, b3_0;
  half8 a0_1, a1_1, b0_1, b1_1, b2_1, b3_1;
  half8 a0_2, a1_2, b0_2, b1_2, b2_2, b3_2;
  half8 a0_3, a1_3, b0_3, b1_3, b2_3, b3_3;

  LOADF(0, 0) LOADF(1, 1) LOADF(2, 2) LOADF(3, 3)

  for (int ks = 0; ks < KSTEPS; ks += 4) {
    MFMA8(0) if (ks + 4 < KSTEPS) { LOADF(0, ks + 4) }
    MFMA8(1) if (ks + 5 < KSTEPS) { LOADF(1, ks + 5) }
    MFMA8(2) if (ks + 6 < KSTEPS) { LOADF(2, ks + 6) }
    MFMA8(3) if (ks + 7 < KSTEPS) { LOADF(3, ks + 7) }
  }

  const float bi = bias[m], bf = bias[HID + m], bg = bias[2 * HID + m],
              bo = bias[3 * HID + m];
  float xwi = 0.f, xwf = 0.f, xwg = 0.f, xwo = 0.f, wl = 0.f;
  if constexpr (L0) {
    xwi = wih0[m]; xwf = wih0[HID + m]; xwg = wih0[2 * HID + m]; xwo = wih0[3 * HID + m];
  } else {
    wl = wlin[m];
  }

  float yv0[4], yv1[4];

#define EPILOG(AI, AF, AG, AO, BOFF, YV)                                       \
  _Pragma("unroll") for (int r = 0; r < 4; ++r) {                              \
    const int b = 32 * w + (BOFF) + 4 * lhi + r;                               \
    float gi = AI[r] + bi, gf = AF[r] + bf, gg = AG[r] + bg, go = AO[r] + bo;  \
    if constexpr (L0) {                                                        \
      float xv = xcol[b * SEQ];                                                \
      gi += xv * xwi; gf += xv * xwf; gg += xv * xwg; go += xv * xwo;          \
    }                                                                          \
    float co = C[b * HID + m];                                                 \
    float cn = sigm(gf) * co + sigm(gi) * tanh_(gg);                           \
    float hn = sigm(go) * tanh_(cn);                                           \
    C[b * HID + m] = cn;                                                       \
    Hout[(size_t)b * AST + m] = (f16)hn;                                       \
    YV[r] = hn;                                                                \
  }

  EPILOG(acc00, acc01, acc02, acc03, 0, yv0)
  EPILOG(acc10, acc11, acc12, acc13, 16, yv1)
#undef EPILOG

  if constexpr (!L0) {
#pragma unroll
    for (int mf = 0; mf < 2; ++mf) {
#pragma unroll
      for (int r = 0; r < 4; ++r) {
        float v = (mf ? yv1[r] : yv0[r]) * wl;
        v += __shfl_xor(v, 1);
        v += __shfl_xor(v, 2);
        v += __shfl_xor(v, 4);
        v += __shfl_xor(v, 8);
        if (l15 == 0) {
          const int b = 32 * w + 16 * mf + 4 * lhi + r;
          ypt[(b << 6) + ublk] = v;
        }
      }
    }
  }
}

// Kernel K_t: blocks [0,64) do layer0 step t; blocks [64,128) do layer1 step t-1.
__global__ __launch_bounds__(256) void step_kernel(
    int t, const f16* __restrict__ bufA, f16* __restrict__ bufB,
    const f16* __restrict__ whh0, const f16* __restrict__ w1cat,
    const float* __restrict__ bias0, const float* __restrict__ bias1,
    float* __restrict__ c0, float* __restrict__ c1,
    const float* __restrict__ X, const float* __restrict__ wih0col,
    const float* __restrict__ wlin, float* __restrict__ yp) {
  const int bid = blockIdx.x;
  if (bid < NBL) {
    if (t <= SEQ)
      lstm_tile<32, true>(bufA, bufB, whh0, bias0, c0, X + (t - 1), wih0col,
                          nullptr, nullptr, bid);
  } else {
    if (t >= 2)
      lstm_tile<64, false>(bufA, bufB + HID, w1cat, bias1, c1, nullptr, nullptr,
                           wlin, yp + (size_t)(t - 2) * NBAT * NBL, bid - NBL);
  }
}

__global__ __launch_bounds__(256) void final_kernel(const float* __restrict__ yp,
                                                    const float* __restrict__ blin,
                                                    float* __restrict__ out) {
  const int i = blockIdx.x * blockDim.x + threadIdx.x;  // 0..32767
  const int tt = i >> 7, b = i & 127;
  const float* p = yp + (size_t)i * NBL;
  float s = 0.f;
#pragma unroll
  for (int j = 0; j < NBL; ++j) s += p[j];
  out[b * SEQ + tt] = s + blin[0];
}

__global__ __launch_bounds__(256) void prologue(
    const float* __restrict__ Wih0, const float* __restrict__ Whh0,
    const float* __restrict__ bih0, const float* __restrict__ bhh0,
    const float* __restrict__ Wih1, const float* __restrict__ Whh1,
    const float* __restrict__ bih1, const float* __restrict__ bhh1,
    f16* __restrict__ whh0h, f16* __restrict__ w1cat, float* __restrict__ bias0,
    float* __restrict__ bias1, float* __restrict__ wih0col,
    f16* __restrict__ buf0, f16* __restrict__ buf1, float* __restrict__ c0,
    float* __restrict__ c1) {
  const int gs = gridDim.x * blockDim.x;
  const int g = blockIdx.x * blockDim.x + threadIdx.x;
  for (int i = g; i < 4096 * 1024; i += gs) whh0h[i] = (f16)Whh0[i];
  for (int i = g; i < 4096 * 2048; i += gs) {
    int j = i >> 11, k = i & 2047;
    w1cat[i] = (f16)(k < 1024 ? Wih1[j * 1024 + k] : Whh1[j * 1024 + k - 1024]);
  }
  for (int i = g; i < 4096; i += gs) {
    bias0[i] = bih0[i] + bhh0[i];
    bias1[i] = bih1[i] + bhh1[i];
    wih0col[i] = Wih0[i];
  }
  for (int i = g; i < NBAT * AST; i += gs) {
    buf0[i] = (f16)0.f;
    buf1[i] = (f16)0.f;
  }
  for (int i = g; i < NBAT * HID; i += gs) {
    c0[i] = 0.f;
    c1[i] = 0.f;
  }
}

extern "C" void kernel_launch(void* const* d_in, const int* in_sizes, int n_in,
                              void* d_out, int out_size, void* d_ws,
                              size_t ws_size, hipStream_t stream) {
  const float* X = (const float*)d_in[0];
  const float* Wih0 = (const float*)d_in[1];
  const float* Whh0 = (const float*)d_in[2];
  const float* bih0 = (const float*)d_in[3];
  const float* bhh0 = (const float*)d_in[4];
  const float* Wih1 = (const float*)d_in[5];
  const float* Whh1 = (const float*)d_in[6];
  const float* bih1 = (const float*)d_in[7];
  const float* bhh1 = (const float*)d_in[8];
  const float* Wlin = (const float*)d_in[9];
  const float* blin = (const float*)d_in[10];
  float* out = (float*)d_out;

  char* p = (char*)d_ws;
  f16* whh0h = (f16*)p;      p += (size_t)4096 * 1024 * 2;
  f16* w1cat = (f16*)p;      p += (size_t)4096 * 2048 * 2;
  f16* buf0 = (f16*)p;       p += (size_t)NBAT * AST * 2;
  f16* buf1 = (f16*)p;       p += (size_t)NBAT * AST * 2;
  float* c0 = (float*)p;     p += (size_t)NBAT * HID * 4;
  float* c1 = (float*)p;     p += (size_t)NBAT * HID * 4;
  float* bias0 = (float*)p;  p += 4096 * 4;
  float* bias1 = (float*)p;  p += 4096 * 4;
  float* wih0col = (float*)p; p += 4096 * 4;
  float* yp = (float*)p;     p += (size_t)SEQ * NBAT * NBL * 4;  // 8 MB

  prologue<<<2048, 256, 0, stream>>>(Wih0, Whh0, bih0, bhh0, Wih1, Whh1, bih1,
                                     bhh1, whh0h, w1cat, bias0, bias1, wih0col,
                                     buf0, buf1, c0, c1);

  for (int t = 1; t <= SEQ + 1; ++t) {
    const f16* bufA = (t & 1) ? buf0 : buf1;  // read parity (t+1)&1
    f16* bufB = (t & 1) ? buf1 : buf0;        // write parity t&1
    step_kernel<<<2 * NBL, 256, 0, stream>>>(t, bufA, bufB, whh0h, w1cat, bias0,
                                             bias1, c0, c1, X, wih0col, Wlin, yp);
  }

  final_kernel<<<NBAT, 256, 0, stream>>>(yp, blin, out);
}

// Round 2
// 8788.438 us; speedup vs baseline: 1.4114x; 1.4114x over previous
//
#include <hip/hip_runtime.h>
#include <stdint.h>

typedef _Float16 f16;
typedef f16 half8 __attribute__((ext_vector_type(8)));
typedef float f32x4 __attribute__((ext_vector_type(4)));

#define AS1 __attribute__((address_space(1)))
#define AS3 __attribute__((address_space(3)))

constexpr int HID = 1024;
constexpr int NBAT = 128;
constexpr int SEQ = 256;
constexpr int NBLK = 192;          // 64 L0 + 64 L1a + 64 L1b
constexpr int UPB = 16;            // hidden units per block
constexpr int HROWB = 2048;        // h row bytes (1024 f16)
constexpr int WROWB = 2064;        // padded LDS W row bytes (2048 + 16)
constexpr int WLDS = 64 * WROWB;   // 132096 B
constexpr int CHB = 8192;          // A-chunk bytes (128 rows x 32 k x 2B)
constexpr int NCH = 32;            // K=1024 / 32
constexpr int LDS_TOTAL = WLDS + 3 * CHB;  // 156672 <= 163840

__device__ __forceinline__ float sigm(float x) { return 1.0f / (1.0f + __expf(-x)); }
__device__ __forceinline__ float tanh_(float x) {
  float e = __expf(2.0f * x);
  return (e - 1.0f) / (e + 1.0f);
}

__device__ __forceinline__ void gl_lds16(const void* g, void* l) {
  __builtin_amdgcn_global_load_lds((const AS1 uint32_t*)g, (AS3 uint32_t*)l, 16, 0, 0);
}

__device__ __forceinline__ void spin_ge(int* p, int target) {
  if (threadIdx.x == 0) {
    uint64_t t0 = __builtin_amdgcn_s_memtime();
    while (__hip_atomic_load(p, __ATOMIC_RELAXED, __HIP_MEMORY_SCOPE_AGENT) < target) {
      __builtin_amdgcn_s_sleep(8);
      if (__builtin_amdgcn_s_memtime() - t0 > (1ULL << 29)) break;  // bounded on pathology
    }
    __threadfence();  // acquire: invalidate stale cache lines once
  }
  __syncthreads();
}

// block types: 0 = layer0 (Whh0, reads h0);  1 = layer1-ih (Wih1, reads h0, writes partial)
//              2 = layer1-hh (Whh1, reads h1, combines partial, cell + y)
__global__ __launch_bounds__(256, 1) void lstm_persist(
    const float* __restrict__ X,
    const float* __restrict__ Wih0, const float* __restrict__ Whh0,
    const float* __restrict__ bih0, const float* __restrict__ bhh0,
    const float* __restrict__ Wih1, const float* __restrict__ Whh1,
    const float* __restrict__ bih1, const float* __restrict__ bhh1,
    const float* __restrict__ Wlin,
    f16* __restrict__ hb0, f16* __restrict__ hb1,  // [2][128][1024] each
    float* __restrict__ pbuf,                      // [2][64][8192]
    float* __restrict__ yp,                        // [256][128][64]
    int* __restrict__ bar, int* __restrict__ flags) {
  extern __shared__ char smem[];
  char* Wl = smem;
  char* Ach = smem + WLDS;

  const int bid = blockIdx.x;
  const int type = bid >> 6;
  const int j = bid & 63;
  const int u0 = j * UPB;
  const int tid = threadIdx.x;
  const int w = tid >> 6, l = tid & 63;
  const int l15 = l & 15, lhi = l >> 4;
  const int m_unit = u0 + l15;

  // ---- one-time W preload: f32 global -> f16 LDS (padded rows) ----
  const float* Wsrc = (type == 0) ? Whh0 : (type == 1) ? Wih1 : Whh1;
  for (int it = 0; it < 256; ++it) {
    int e = it * 256 + tid;
    int r = e >> 10, k = e & 1023;                      // LDS row r = gate*16 + unit_local
    int grow = (r >> 4) * HID + u0 + (r & 15);          // global gate-row
    *(f16*)(Wl + r * WROWB + 2 * k) = (f16)Wsrc[(size_t)grow * HID + k];
  }

  // ---- per-lane constants ----
  float bi = 0, bf = 0, bg = 0, bo = 0, wi_i = 0, wi_f = 0, wi_g = 0, wi_o = 0, wl = 0;
  if (type == 0) {
    bi = bih0[m_unit] + bhh0[m_unit];
    bf = bih0[HID + m_unit] + bhh0[HID + m_unit];
    bg = bih0[2 * HID + m_unit] + bhh0[2 * HID + m_unit];
    bo = bih0[3 * HID + m_unit] + bhh0[3 * HID + m_unit];
    wi_i = Wih0[m_unit]; wi_f = Wih0[HID + m_unit];
    wi_g = Wih0[2 * HID + m_unit]; wi_o = Wih0[3 * HID + m_unit];
  } else if (type == 2) {
    bi = bih1[m_unit] + bhh1[m_unit];
    bf = bih1[HID + m_unit] + bhh1[HID + m_unit];
    bg = bih1[2 * HID + m_unit] + bhh1[2 * HID + m_unit];
    bo = bih1[3 * HID + m_unit] + bhh1[3 * HID + m_unit];
    wl = Wlin[m_unit];
  }
  float cst[8];
#pragma unroll
  for (int q = 0; q < 8; ++q) cst[q] = 0.f;
  __syncthreads();

  const char* Wbase = Wl + l15 * WROWB + lhi * 16;
  const char* Abase0 = Ach + w * 2048 + (lhi * 32 + l15) * 16;

  for (int i = 1; i <= SEQ + 1; ++i) {
    if (i >= 2) spin_ge(&bar[i - 1], NBLK);

    const bool active = (type == 0) ? (i <= SEQ) : (i >= 2);
    if (active) {
      const char* Asrc = (type == 2)
          ? (const char*)(hb1 + (size_t)(i & 1) * NBAT * HID)          // h1(i-2)
          : (const char*)(hb0 + (size_t)((i - 1) & 1) * NBAT * HID);   // h0(i-1)
      float xr[8];
      if (type == 0) {
#pragma unroll
        for (int mf = 0; mf < 2; ++mf)
#pragma unroll
          for (int r = 0; r < 4; ++r)
            xr[mf * 4 + r] = X[(32 * w + 16 * mf + 4 * lhi + r) * SEQ + (i - 1)];
        asm volatile("s_waitcnt vmcnt(0)" ::: "memory");  // keep loop vmcnt counting clean
        __builtin_amdgcn_sched_barrier(0);
      }

      // per-lane global source; per-wave-uniform LDS dest (gl_lds adds lane*16)
      const char* arow = Asrc + (size_t)(32 * w + (l & 31)) * HROWB + (l >> 5) * 16;
      char* dbase = Ach + w * 2048;
#define ISSUE(ck, buf)                                        \
  gl_lds16(arow + (ck) * 64, dbase + (buf) * CHB);            \
  gl_lds16(arow + (ck) * 64 + 32, dbase + (buf) * CHB + 1024);

      ISSUE(0, 0) ISSUE(1, 1) ISSUE(2, 2)

      f32x4 acc[2][4];
#pragma unroll
      for (int mf = 0; mf < 2; ++mf)
#pragma unroll
        for (int n = 0; n < 4; ++n) acc[mf][n] = f32x4{0.f, 0.f, 0.f, 0.f};

      for (int ck = 0; ck < NCH; ++ck) {
        if (ck <= NCH - 3) { asm volatile("s_waitcnt vmcnt(4)" ::: "memory"); }
        else if (ck == NCH - 2) { asm volatile("s_waitcnt vmcnt(2)" ::: "memory"); }
        else { asm volatile("s_waitcnt vmcnt(0)" ::: "memory"); }
        __builtin_amdgcn_sched_barrier(0);
        const int buf = ck % 3;
        half8 a0 = *(const half8*)(Abase0 + buf * CHB);
        half8 a1 = *(const half8*)(Abase0 + buf * CHB + 256);
        half8 b0 = *(const half8*)(Wbase + ck * 64);
        half8 b1 = *(const half8*)(Wbase + 16 * WROWB + ck * 64);
        half8 b2 = *(const half8*)(Wbase + 32 * WROWB + ck * 64);
        half8 b3 = *(const half8*)(Wbase + 48 * WROWB + ck * 64);
        asm volatile("s_waitcnt lgkmcnt(0)" ::: "memory");  // frags in regs before overwrite
        __builtin_amdgcn_sched_barrier(0);
        if (ck < NCH - 3) { ISSUE(ck + 3, buf) }
        acc[0][0] = __builtin_amdgcn_mfma_f32_16x16x32_f16(a0, b0, acc[0][0], 0, 0, 0);
        acc[0][1] = __builtin_amdgcn_mfma_f32_16x16x32_f16(a0, b1, acc[0][1], 0, 0, 0);
        acc[0][2] = __builtin_amdgcn_mfma_f32_16x16x32_f16(a0, b2, acc[0][2], 0, 0, 0);
        acc[0][3] = __builtin_amdgcn_mfma_f32_16x16x32_f16(a0, b3, acc[0][3], 0, 0, 0);
        acc[1][0] = __builtin_amdgcn_mfma_f32_16x16x32_f16(a1, b0, acc[1][0], 0, 0, 0);
        acc[1][1] = __builtin_amdgcn_mfma_f32_16x16x32_f16(a1, b1, acc[1][1], 0, 0, 0);
        acc[1][2] = __builtin_amdgcn_mfma_f32_16x16x32_f16(a1, b2, acc[1][2], 0, 0, 0);
        acc[1][3] = __builtin_amdgcn_mfma_f32_16x16x32_f16(a1, b3, acc[1][3], 0, 0, 0);
      }
#undef ISSUE

      if (type == 1) {
        // write partial gates + flag for partner
        f32x4* pp = (f32x4*)(pbuf + ((size_t)(i & 1) * 64 + j) * 8192) + (w * 64 + l) * 8;
#pragma unroll
        for (int mf = 0; mf < 2; ++mf)
#pragma unroll
          for (int n = 0; n < 4; ++n) pp[mf * 4 + n] = acc[mf][n];
        __syncthreads();  // drains stores (vmcnt 0) before fence+flag
        if (tid == 0) {
          __threadfence();
          __hip_atomic_store(&flags[i * 64 + j], 1, __ATOMIC_RELEASE, __HIP_MEMORY_SCOPE_AGENT);
        }
      } else {
        if (type == 2) {
          spin_ge(&flags[i * 64 + j], 1);
          const f32x4* pp =
              (const f32x4*)(pbuf + ((size_t)(i & 1) * 64 + j) * 8192) + (w * 64 + l) * 8;
#pragma unroll
          for (int mf = 0; mf < 2; ++mf)
#pragma unroll
            for (int n = 0; n < 4; ++n) acc[mf][n] += pp[mf * 4 + n];
        }
        f16* Hw = (type == 0) ? hb0 + (size_t)(i & 1) * NBAT * HID
                              : hb1 + (size_t)((i - 1) & 1) * NBAT * HID;
        float hn_v[8];
#pragma unroll
        for (int mf = 0; mf < 2; ++mf) {
#pragma unroll
          for (int r = 0; r < 4; ++r) {
            int b = 32 * w + 16 * mf + 4 * lhi + r;
            float gi = acc[mf][0][r] + bi;
            float gf = acc[mf][1][r] + bf;
            float gg = acc[mf][2][r] + bg;
            float go = acc[mf][3][r] + bo;
            if (type == 0) {
              float xv = xr[mf * 4 + r];
              gi += xv * wi_i; gf += xv * wi_f; gg += xv * wi_g; go += xv * wi_o;
            }
            float cn = sigm(gf) * cst[mf * 4 + r] + sigm(gi) * tanh_(gg);
            float hn = sigm(go) * tanh_(cn);
            cst[mf * 4 + r] = cn;
            Hw[(size_t)b * HID + m_unit] = (f16)hn;
            hn_v[mf * 4 + r] = hn;
          }
        }
        if (type == 2) {
#pragma unroll
          for (int q = 0; q < 8; ++q) {
            float v = hn_v[q] * wl;
            v += __shfl_xor(v, 1); v += __shfl_xor(v, 2);
            v += __shfl_xor(v, 4); v += __shfl_xor(v, 8);
            if (l15 == 0) {
              int b = 32 * w + 16 * (q >> 2) + 4 * lhi + (q & 3);
              yp[(size_t)(i - 2) * NBAT * 64 + b * 64 + j] = v;
            }
          }
        }
      }
    }

    __syncthreads();  // drains this block's stores
    if (tid == 0) {
      __threadfence();  // writeback L2 -> device visible
      __hip_atomic_fetch_add(&bar[i], 1, __ATOMIC_RELEASE, __HIP_MEMORY_SCOPE_AGENT);
    }
  }
}

__global__ __launch_bounds__(256) void zero_ws(f16* hb0, f16* hb1, int* bar, int* flags) {
  int g = blockIdx.x * 256 + threadIdx.x, gs = gridDim.x * 256;
  for (int idx = g; idx < 2 * NBAT * HID; idx += gs) { hb0[idx] = (f16)0.f; hb1[idx] = (f16)0.f; }
  for (int idx = g; idx < 512; idx += gs) bar[idx] = 0;
  for (int idx = g; idx < 258 * 64; idx += gs) flags[idx] = 0;
}

__global__ __launch_bounds__(256) void final_kernel(const float* __restrict__ yp,
                                                    const float* __restrict__ blin,
                                                    float* __restrict__ out) {
  const int i = blockIdx.x * blockDim.x + threadIdx.x;  // 0..32767
  const int tt = i >> 7, b = i & 127;
  const float* p = yp + (size_t)tt * NBAT * 64 + b * 64;
  float s = 0.f;
#pragma unroll
  for (int q = 0; q < 64; ++q) s += p[q];
  out[b * SEQ + tt] = s + blin[0];
}

extern "C" void kernel_launch(void* const* d_in, const int* in_sizes, int n_in,
                              void* d_out, int out_size, void* d_ws, size_t ws_size,
                              hipStream_t stream) {
  const float* X = (const float*)d_in[0];
  const float* Wih0 = (const float*)d_in[1];
  const float* Whh0 = (const float*)d_in[2];
  const float* bih0 = (const float*)d_in[3];
  const float* bhh0 = (const float*)d_in[4];
  const float* Wih1 = (const float*)d_in[5];
  const float* Whh1 = (const float*)d_in[6];
  const float* bih1 = (const float*)d_in[7];
  const float* bhh1 = (const float*)d_in[8];
  const float* Wlin = (const float*)d_in[9];
  const float* blin = (const float*)d_in[10];
  float* out = (float*)d_out;

  char* p = (char*)d_ws;
  f16* hb0 = (f16*)p;     p += (size_t)2 * NBAT * HID * 2;
  f16* hb1 = (f16*)p;     p += (size_t)2 * NBAT * HID * 2;
  float* pbuf = (float*)p; p += (size_t)2 * 64 * 8192 * 4;   // 4 MB
  float* yp = (float*)p;   p += (size_t)SEQ * NBAT * 64 * 4; // 8 MB
  int* bar = (int*)p;      p += 512 * 4;
  int* flags = (int*)p;    p += 258 * 64 * 4;

  hipFuncSetAttribute((const void*)lstm_persist,
                      hipFuncAttributeMaxDynamicSharedMemorySize, LDS_TOTAL);

  zero_ws<<<256, 256, 0, stream>>>(hb0, hb1, bar, flags);

  lstm_persist<<<NBLK, 256, LDS_TOTAL, stream>>>(
      X, Wih0, Whh0, bih0, bhh0, Wih1, Whh1, bih1, bhh1, Wlin,
      hb0, hb1, pbuf, yp, bar, flags);

  final_kernel<<<NBAT, 256, 0, stream>>>(yp, blin, out);
}

// Round 9
// 8116.653 us; speedup vs baseline: 1.5283x; 1.0828x over previous
//
#include <hip/hip_runtime.h>
#include <stdint.h>

typedef _Float16 f16;
typedef f16 half8 __attribute__((ext_vector_type(8)));
typedef float f32x4 __attribute__((ext_vector_type(4)));

#define AS1 __attribute__((address_space(1)))
#define AS3 __attribute__((address_space(3)))

constexpr int HID = 1024;
constexpr int NBAT = 128;
constexpr int SEQ = 256;
constexpr int NL0 = 64;          // layer0 blocks: 16 units, K=1024
constexpr int NL1 = 128;         // layer1 blocks: 8 units,  K=2048 ([Wih1|Whh1])
constexpr int NBLK = NL0 + NL1;  // 192
constexpr int HROWB = 4096;      // Hcat row bytes: [h0(1024) | h1(1024)] f16
constexpr int WROWB0 = 2064;     // L0 LDS W row: 2048B + 16 pad
constexpr int WROWB1 = 4112;     // L1 LDS W row: 4096B + 16 pad
constexpr int ZOFF = 32 * WROWB1;       // 131584: start of shared zero band (L1)
constexpr int ZBYTES = 4160;            // covers ck*64 + lhi*16 (<= 4080) + slack
constexpr int WLDS = ZOFF + ZBYTES;     // 135744 >= 64*WROWB0 (132096)
constexpr int CHB = 8192;               // staged A chunk: 128 rows x 64B
constexpr int LDS_TOTAL = WLDS + 3 * CHB;  // 160320 <= 163840

__device__ __forceinline__ float sigm(float x) { return 1.0f / (1.0f + __expf(-x)); }
__device__ __forceinline__ float tanh_(float x) {
  float e = __expf(2.0f * x);
  return (e - 1.0f) / (e + 1.0f);
}
__device__ __forceinline__ void gl_lds16(const void* g, void* l) {
  __builtin_amdgcn_global_load_lds((const AS1 uint32_t*)g, (AS3 uint32_t*)l, 16, 0, 0);
}
__device__ __forceinline__ void vm0() {
  asm volatile("s_waitcnt vmcnt(0)" ::: "memory");
}
// R2-proven acquire: tid0 spins (relaxed), then full __threadfence (inv), then
// block-wide syncthreads. Copied verbatim from the round-2 passing kernel.
__device__ __forceinline__ void spin_ge(int* p, int target) {
  if (threadIdx.x == 0) {
    uint64_t t0 = __builtin_amdgcn_s_memtime();
    while (__hip_atomic_load(p, __ATOMIC_RELAXED, __HIP_MEMORY_SCOPE_AGENT) < target) {
      __builtin_amdgcn_s_sleep(8);
      if (__builtin_amdgcn_s_memtime() - t0 > (1ULL << 29)) break;  // bounded on pathology
    }
    __threadfence();  // acquire: invalidate stale cache lines
  }
  __syncthreads();
}

__global__ __launch_bounds__(256, 1) void lstm_persist(
    const float* __restrict__ X,
    const float* __restrict__ Wih0, const float* __restrict__ Whh0,
    const float* __restrict__ bih0, const float* __restrict__ bhh0,
    const float* __restrict__ Wih1, const float* __restrict__ Whh1,
    const float* __restrict__ bih1, const float* __restrict__ bhh1,
    const float* __restrict__ Wlin,
    f16* __restrict__ Hcat,   // [2][128][2048]  ([h0|h1] per row, parity slots)
    float* __restrict__ yp,   // [256][128][128] per-L1-block y partials
    int* __restrict__ bar) {  // bar[i]: per-step arrival count (R2-proven)
  extern __shared__ char smem[];
  char* Wl = smem;
  char* Ach = smem + WLDS;

  const int bid = blockIdx.x, tid = threadIdx.x;
  const bool isL0 = bid < NL0;
  const int j = isL0 ? bid : bid - NL0;
  const int w = tid >> 6, l = tid & 63;
  const int l15 = l & 15, lhi = l >> 4;

  // ---- one-time W preload: f32 global -> f16 LDS (padded rows) ----
  if (isL0) {
    for (int it = 0; it < 256; ++it) {
      int e = it * 256 + tid;
      int r = e >> 10, k = e & 1023;                 // LDS row r = gate*16 + u
      int grow = (r >> 4) * HID + j * 16 + (r & 15);
      *(f16*)(Wl + r * WROWB0 + 2 * k) = (f16)Whh0[(size_t)grow * HID + k];
    }
  } else {
    for (int it = 0; it < 256; ++it) {
      int e = it * 256 + tid;
      int r = e >> 11, k = e & 2047;                 // LDS row r = gate*8 + u
      int grow = (r >> 3) * HID + j * 8 + (r & 7);
      float v = (k < 1024) ? Wih1[(size_t)grow * HID + k]
                           : Whh1[(size_t)grow * HID + (k - 1024)];
      *(f16*)(Wl + r * WROWB1 + 2 * k) = (f16)v;
    }
    for (int e = tid; e < ZBYTES / 2; e += 256)      // shared zero band (N-pad)
      *(f16*)(Wl + ZOFF + 2 * e) = (f16)0.f;
  }

  // ---- per-lane constants ----
  float bi, bf, bg, bo, wi_i = 0, wi_f = 0, wi_g = 0, wi_o = 0, wl = 0;
  if (isL0) {
    int m = j * 16 + l15;
    bi = bih0[m] + bhh0[m];
    bf = bih0[HID + m] + bhh0[HID + m];
    bg = bih0[2 * HID + m] + bhh0[2 * HID + m];
    bo = bih0[3 * HID + m] + bhh0[3 * HID + m];
    wi_i = Wih0[m]; wi_f = Wih0[HID + m];
    wi_g = Wih0[2 * HID + m]; wi_o = Wih0[3 * HID + m];
  } else {
    int u = j * 8 + (l15 & 7);
    bi = bih1[u] + bhh1[u];
    bf = bih1[HID + u] + bhh1[HID + u];
    bg = bih1[2 * HID + u] + bhh1[2 * HID + u];
    bo = bih1[3 * HID + u] + bhh1[3 * HID + u];
    wl = (l15 < 8) ? Wlin[u] : 0.f;  // pad lanes contribute 0 to y
  }
  float cst[8];
#pragma unroll
  for (int q = 0; q < 8; ++q) cst[q] = 0.f;
  __syncthreads();

  // L0 B pointers: proven 16-unit layout (b tiles at +16/32/48 rows)
  const char* Wb = Wl + l15 * WROWB0 + lhi * 16;
  // L1 B pointers: one per gate; cols 8-15 -> shared zero band (B-frag = 0)
  const char* Wg0 = Wl + ((l15 < 8) ? (0 * 8 + l15) * WROWB1 : ZOFF) + lhi * 16;
  const char* Wg1 = Wl + ((l15 < 8) ? (1 * 8 + l15) * WROWB1 : ZOFF) + lhi * 16;
  const char* Wg2 = Wl + ((l15 < 8) ? (2 * 8 + l15) * WROWB1 : ZOFF) + lhi * 16;
  const char* Wg3 = Wl + ((l15 < 8) ? (3 * 8 + l15) * WROWB1 : ZOFF) + lhi * 16;

  const char* Ab = Ach + w * 2048 + (lhi * 32 + l15) * 16;
  char* dbase = Ach + w * 2048;

#define ISSUE(ck, buf)                                        \
  gl_lds16(arow + (ck) * 64, dbase + (buf) * CHB);            \
  gl_lds16(arow + (ck) * 64 + 32, dbase + (buf) * CHB + 1024);

  for (int i = 1; i <= SEQ + 1; ++i) {
    if (i >= 2) spin_ge(&bar[i - 1], NBLK);  // acquire: step i-1 h visible

    const bool active = isL0 ? (i <= SEQ) : (i >= 2);
    if (active) {
      const char* Asrc = (const char*)Hcat + (size_t)((i - 1) & 1) * NBAT * HROWB;
      const char* arow = Asrc + (size_t)(32 * w + (l & 31)) * HROWB + (l >> 5) * 16;
      f16* Hw = Hcat + (size_t)(i & 1) * NBAT * 2048;

      if (isL0) {
        // -------- layer0: 0-idx step i-1, K=1024 (h0 half), 4 gate-tiles --------
        float xr[8];
#pragma unroll
        for (int mf = 0; mf < 2; ++mf)
#pragma unroll
          for (int r = 0; r < 4; ++r)
            xr[mf * 4 + r] = X[(32 * w + 16 * mf + 4 * lhi + r) * SEQ + (i - 1)];
        vm0();
        __builtin_amdgcn_sched_barrier(0);

        ISSUE(0, 0) ISSUE(1, 1) ISSUE(2, 2)
        f32x4 acc[2][4];
#pragma unroll
        for (int mf = 0; mf < 2; ++mf)
#pragma unroll
          for (int n = 0; n < 4; ++n) acc[mf][n] = f32x4{0.f, 0.f, 0.f, 0.f};

        for (int ck = 0; ck < 32; ++ck) {
          if (ck <= 29) { asm volatile("s_waitcnt vmcnt(4)" ::: "memory"); }
          else if (ck == 30) { asm volatile("s_waitcnt vmcnt(2)" ::: "memory"); }
          else { asm volatile("s_waitcnt vmcnt(0)" ::: "memory"); }
          __builtin_amdgcn_sched_barrier(0);
          const int buf = ck % 3;
          half8 a0 = *(const half8*)(Ab + buf * CHB);
          half8 a1 = *(const half8*)(Ab + buf * CHB + 256);
          half8 b0 = *(const half8*)(Wb + ck * 64);
          half8 b1 = *(const half8*)(Wb + 16 * WROWB0 + ck * 64);
          half8 b2 = *(const half8*)(Wb + 32 * WROWB0 + ck * 64);
          half8 b3 = *(const half8*)(Wb + 48 * WROWB0 + ck * 64);
          asm volatile("s_waitcnt lgkmcnt(0)" ::: "memory");
          __builtin_amdgcn_sched_barrier(0);
          if (ck < 29) { ISSUE(ck + 3, buf) }
          acc[0][0] = __builtin_amdgcn_mfma_f32_16x16x32_f16(a0, b0, acc[0][0], 0, 0, 0);
          acc[0][1] = __builtin_amdgcn_mfma_f32_16x16x32_f16(a0, b1, acc[0][1], 0, 0, 0);
          acc[0][2] = __builtin_amdgcn_mfma_f32_16x16x32_f16(a0, b2, acc[0][2], 0, 0, 0);
          acc[0][3] = __builtin_amdgcn_mfma_f32_16x16x32_f16(a0, b3, acc[0][3], 0, 0, 0);
          acc[1][0] = __builtin_amdgcn_mfma_f32_16x16x32_f16(a1, b0, acc[1][0], 0, 0, 0);
          acc[1][1] = __builtin_amdgcn_mfma_f32_16x16x32_f16(a1, b1, acc[1][1], 0, 0, 0);
          acc[1][2] = __builtin_amdgcn_mfma_f32_16x16x32_f16(a1, b2, acc[1][2], 0, 0, 0);
          acc[1][3] = __builtin_amdgcn_mfma_f32_16x16x32_f16(a1, b3, acc[1][3], 0, 0, 0);
        }

#pragma unroll
        for (int mf = 0; mf < 2; ++mf) {
#pragma unroll
          for (int r = 0; r < 4; ++r) {
            int b = 32 * w + 16 * mf + 4 * lhi + r;
            float xv = xr[mf * 4 + r];
            float gi = acc[mf][0][r] + bi + xv * wi_i;
            float gf = acc[mf][1][r] + bf + xv * wi_f;
            float gg = acc[mf][2][r] + bg + xv * wi_g;
            float go = acc[mf][3][r] + bo + xv * wi_o;
            float cn = sigm(gf) * cst[mf * 4 + r] + sigm(gi) * tanh_(gg);
            float hn = sigm(go) * tanh_(cn);
            cst[mf * 4 + r] = cn;
            Hw[(size_t)b * 2048 + j * 16 + l15] = (f16)hn;
          }
        }
      } else {
        // ---- layer1: 0-idx step i-2, K=2048 full [h0|h1] row, 4 gate-tiles ----
        //      (R1-proven layout; N cols 8-15 are zero-padded via the zero band)
        ISSUE(0, 0) ISSUE(1, 1) ISSUE(2, 2)
        f32x4 acc[2][4];
#pragma unroll
        for (int mf = 0; mf < 2; ++mf)
#pragma unroll
          for (int n = 0; n < 4; ++n) acc[mf][n] = f32x4{0.f, 0.f, 0.f, 0.f};

        for (int ck = 0; ck < 64; ++ck) {
          if (ck <= 61) { asm volatile("s_waitcnt vmcnt(4)" ::: "memory"); }
          else if (ck == 62) { asm volatile("s_waitcnt vmcnt(2)" ::: "memory"); }
          else { asm volatile("s_waitcnt vmcnt(0)" ::: "memory"); }
          __builtin_amdgcn_sched_barrier(0);
          const int buf = ck % 3;
          half8 a0 = *(const half8*)(Ab + buf * CHB);
          half8 a1 = *(const half8*)(Ab + buf * CHB + 256);
          half8 b0 = *(const half8*)(Wg0 + ck * 64);
          half8 b1 = *(const half8*)(Wg1 + ck * 64);
          half8 b2 = *(const half8*)(Wg2 + ck * 64);
          half8 b3 = *(const half8*)(Wg3 + ck * 64);
          asm volatile("s_waitcnt lgkmcnt(0)" ::: "memory");
          __builtin_amdgcn_sched_barrier(0);
          if (ck < 61) { ISSUE(ck + 3, buf) }
          acc[0][0] = __builtin_amdgcn_mfma_f32_16x16x32_f16(a0, b0, acc[0][0], 0, 0, 0);
          acc[0][1] = __builtin_amdgcn_mfma_f32_16x16x32_f16(a0, b1, acc[0][1], 0, 0, 0);
          acc[0][2] = __builtin_amdgcn_mfma_f32_16x16x32_f16(a0, b2, acc[0][2], 0, 0, 0);
          acc[0][3] = __builtin_amdgcn_mfma_f32_16x16x32_f16(a0, b3, acc[0][3], 0, 0, 0);
          acc[1][0] = __builtin_amdgcn_mfma_f32_16x16x32_f16(a1, b0, acc[1][0], 0, 0, 0);
          acc[1][1] = __builtin_amdgcn_mfma_f32_16x16x32_f16(a1, b1, acc[1][1], 0, 0, 0);
          acc[1][2] = __builtin_amdgcn_mfma_f32_16x16x32_f16(a1, b2, acc[1][2], 0, 0, 0);
          acc[1][3] = __builtin_amdgcn_mfma_f32_16x16x32_f16(a1, b3, acc[1][3], 0, 0, 0);
        }

        // R2-proven epilogue shape: all four gates lane-local, no exchange.
#pragma unroll
        for (int mf = 0; mf < 2; ++mf) {
#pragma unroll
          for (int r = 0; r < 4; ++r) {
            int b = 32 * w + 16 * mf + 4 * lhi + r;
            float gi = acc[mf][0][r] + bi;
            float gf = acc[mf][1][r] + bf;
            float gg = acc[mf][2][r] + bg;
            float go = acc[mf][3][r] + bo;
            float cn = sigm(gf) * cst[mf * 4 + r] + sigm(gi) * tanh_(gg);
            float hn = sigm(go) * tanh_(cn);
            cst[mf * 4 + r] = cn;
            if (l15 < 8) Hw[(size_t)b * 2048 + 1024 + j * 8 + l15] = (f16)hn;
            float v = hn * wl;  // wl == 0 on pad lanes
            v += __shfl_xor(v, 1);
            v += __shfl_xor(v, 2);
            v += __shfl_xor(v, 4);
            v += __shfl_xor(v, 8);
            if (l15 == 0)
              yp[(size_t)(i - 2) * NBAT * NL1 + b * NL1 + j] = v;
          }
        }
      }
    }

    // ---- R2-proven release: drain stores, block barrier, full threadfence
    //      (wbl2+inv) from tid0, then the barrier add. ----
    vm0();
    __syncthreads();
    if (tid == 0) {
      __threadfence();
      __hip_atomic_fetch_add(&bar[i], 1, __ATOMIC_RELEASE, __HIP_MEMORY_SCOPE_AGENT);
    }
  }
#undef ISSUE
}

__global__ __launch_bounds__(256) void zero_ws(f16* Hcat, int* bar) {
  int g = blockIdx.x * 256 + threadIdx.x, gs = gridDim.x * 256;
  for (int idx = g; idx < 2 * NBAT * 2048; idx += gs) Hcat[idx] = (f16)0.f;
  for (int idx = g; idx < 512; idx += gs) bar[idx] = 0;
}

__global__ __launch_bounds__(256) void final_kernel(const float* __restrict__ yp,
                                                    const float* __restrict__ blin,
                                                    float* __restrict__ out) {
  const int idx = blockIdx.x * blockDim.x + threadIdx.x;  // 0..32767
  const int t = idx >> 7, b = idx & 127;
  const float* p = yp + ((size_t)t * NBAT + b) * NL1;
  float s = 0.f;
#pragma unroll
  for (int q = 0; q < NL1; ++q) s += p[q];
  out[b * SEQ + t] = s + blin[0];
}

extern "C" void kernel_launch(void* const* d_in, const int* in_sizes, int n_in,
                              void* d_out, int out_size, void* d_ws, size_t ws_size,
                              hipStream_t stream) {
  const float* X = (const float*)d_in[0];
  const float* Wih0 = (const float*)d_in[1];
  const float* Whh0 = (const float*)d_in[2];
  const float* bih0 = (const float*)d_in[3];
  const float* bhh0 = (const float*)d_in[4];
  const float* Wih1 = (const float*)d_in[5];
  const float* Whh1 = (const float*)d_in[6];
  const float* bih1 = (const float*)d_in[7];
  const float* bhh1 = (const float*)d_in[8];
  const float* Wlin = (const float*)d_in[9];
  const float* blin = (const float*)d_in[10];
  float* out = (float*)d_out;

  char* p = (char*)d_ws;
  f16* Hcat = (f16*)p;    p += (size_t)2 * NBAT * 2048 * 2;      // 1 MB
  float* yp = (float*)p;  p += (size_t)SEQ * NBAT * NL1 * 4;     // 16.8 MB
  int* bar = (int*)p;     p += 512 * 4;

  hipFuncSetAttribute((const void*)lstm_persist,
                      hipFuncAttributeMaxDynamicSharedMemorySize, LDS_TOTAL);

  zero_ws<<<256, 256, 0, stream>>>(Hcat, bar);

  lstm_persist<<<NBLK, 256, LDS_TOTAL, stream>>>(
      X, Wih0, Whh0, bih0, bhh0, Wih1, Whh1, bih1, bhh1, Wlin,
      Hcat, yp, bar);

  final_kernel<<<NBAT, 256, 0, stream>>>(yp, blin, out);
}

// Round 10
// 7418.153 us; speedup vs baseline: 1.6722x; 1.0942x over previous
//
#include <hip/hip_runtime.h>
#include <stdint.h>

typedef _Float16 f16;
typedef f16 half8 __attribute__((ext_vector_type(8)));
typedef float f32x4 __attribute__((ext_vector_type(4)));

#define AS1 __attribute__((address_space(1)))
#define AS3 __attribute__((address_space(3)))

constexpr int HID = 1024;
constexpr int NBAT = 128;
constexpr int SEQ = 256;
constexpr int NL0 = 64;          // layer0 blocks: 16 units, K=1024
constexpr int NL1 = 128;         // layer1 blocks: 8 units,  K=2048 ([Wih1|Whh1])
constexpr int NBLK = NL0 + NL1;  // 192
constexpr int HROWB = 4096;      // Hcat row bytes: [h0(1024) | h1(1024)] f16
constexpr int WROWB0 = 2064;     // L0 LDS W row: 2048B + 16 pad
constexpr int WROWB1 = 4112;     // L1 LDS W row: 4096B + 16 pad
constexpr int ZOFF = 32 * WROWB1;       // 131584: start of shared zero band (L1)
constexpr int ZBYTES = 4160;            // covers ck*64 + lhi*16 (<= 4080) + slack
constexpr int WLDS = ZOFF + ZBYTES;     // 135744 >= 64*WROWB0 (132096)
constexpr int CHB = 8192;               // staged A chunk: 128 rows x 64B
constexpr int LDS_TOTAL = WLDS + 3 * CHB;  // 160320 <= 163840

__device__ __forceinline__ float sigm(float x) { return 1.0f / (1.0f + __expf(-x)); }
__device__ __forceinline__ float tanh_(float x) {
  float e = __expf(2.0f * x);
  return (e - 1.0f) / (e + 1.0f);
}
__device__ __forceinline__ void gl_lds16(const void* g, void* l) {
  __builtin_amdgcn_global_load_lds((const AS1 uint32_t*)g, (AS3 uint32_t*)l, 16, 0, 0);
}
__device__ __forceinline__ void vm0() {
  asm volatile("s_waitcnt vmcnt(0)" ::: "memory");
}
__device__ __forceinline__ void spin_until(int* p, int target) {
  uint64_t t0 = __builtin_amdgcn_s_memtime();
  while (__hip_atomic_load(p, __ATOMIC_RELAXED, __HIP_MEMORY_SCOPE_AGENT) < target) {
    __builtin_amdgcn_s_sleep(1);
    if (__builtin_amdgcn_s_memtime() - t0 > (1ULL << 29)) break;  // bounded on pathology
  }
}

__global__ __launch_bounds__(256, 1) void lstm_persist(
    const float* __restrict__ X,
    const float* __restrict__ Wih0, const float* __restrict__ Whh0,
    const float* __restrict__ bih0, const float* __restrict__ bhh0,
    const float* __restrict__ Wih1, const float* __restrict__ Whh1,
    const float* __restrict__ bih1, const float* __restrict__ bhh1,
    const float* __restrict__ Wlin,
    f16* __restrict__ Hcat,   // [2][128][2048]  ([h0|h1] per row, parity slots)
    float* __restrict__ yp,   // [256][128][128] per-L1-block y partials
    int* __restrict__ barA, int* __restrict__ barB, int* __restrict__ elect) {
  extern __shared__ char smem[];
  char* Wl = smem;
  char* Ach = smem + WLDS;

  const int bid = blockIdx.x, tid = threadIdx.x;
  const bool isL0 = bid < NL0;
  const int j = isL0 ? bid : bid - NL0;
  const int w = tid >> 6, l = tid & 63;
  const int l15 = l & 15, lhi = l >> 4;

  int xcd;
  asm volatile("s_getreg_b32 %0, hwreg(HW_REG_XCC_ID)" : "=s"(xcd));
  xcd &= 7;

  // ---- one-time W preload: f32 global -> f16 LDS (padded rows) ----
  if (isL0) {
    for (int it = 0; it < 256; ++it) {
      int e = it * 256 + tid;
      int r = e >> 10, k = e & 1023;                 // LDS row r = gate*16 + u
      int grow = (r >> 4) * HID + j * 16 + (r & 15);
      *(f16*)(Wl + r * WROWB0 + 2 * k) = (f16)Whh0[(size_t)grow * HID + k];
    }
  } else {
    for (int it = 0; it < 256; ++it) {
      int e = it * 256 + tid;
      int r = e >> 11, k = e & 2047;                 // LDS row r = gate*8 + u
      int grow = (r >> 3) * HID + j * 8 + (r & 7);
      float v = (k < 1024) ? Wih1[(size_t)grow * HID + k]
                           : Whh1[(size_t)grow * HID + (k - 1024)];
      *(f16*)(Wl + r * WROWB1 + 2 * k) = (f16)v;
    }
    for (int e = tid; e < ZBYTES / 2; e += 256)      // shared zero band (N-pad)
      *(f16*)(Wl + ZOFF + 2 * e) = (f16)0.f;
  }

  // ---- per-lane constants ----
  float bi, bf, bg, bo, wi_i = 0, wi_f = 0, wi_g = 0, wi_o = 0, wl = 0;
  if (isL0) {
    int m = j * 16 + l15;
    bi = bih0[m] + bhh0[m];
    bf = bih0[HID + m] + bhh0[HID + m];
    bg = bih0[2 * HID + m] + bhh0[2 * HID + m];
    bo = bih0[3 * HID + m] + bhh0[3 * HID + m];
    wi_i = Wih0[m]; wi_f = Wih0[HID + m];
    wi_g = Wih0[2 * HID + m]; wi_o = Wih0[3 * HID + m];
  } else {
    int u = j * 8 + (l15 & 7);
    bi = bih1[u] + bhh1[u];
    bf = bih1[HID + u] + bhh1[HID + u];
    bg = bih1[2 * HID + u] + bhh1[2 * HID + u];
    bo = bih1[3 * HID + u] + bhh1[3 * HID + u];
    wl = (l15 < 8) ? Wlin[u] : 0.f;  // pad lanes contribute 0 to y
  }
  float cst[8];
#pragma unroll
  for (int q = 0; q < 8; ++q) cst[q] = 0.f;
  __syncthreads();

  // L0 B pointers: proven 16-unit layout (b tiles at +16/32/48 rows)
  const char* Wb = Wl + l15 * WROWB0 + lhi * 16;
  // L1 B pointers: one per gate; cols 8-15 -> shared zero band (B-frag = 0)
  const char* Wg0 = Wl + ((l15 < 8) ? (0 * 8 + l15) * WROWB1 : ZOFF) + lhi * 16;
  const char* Wg1 = Wl + ((l15 < 8) ? (1 * 8 + l15) * WROWB1 : ZOFF) + lhi * 16;
  const char* Wg2 = Wl + ((l15 < 8) ? (2 * 8 + l15) * WROWB1 : ZOFF) + lhi * 16;
  const char* Wg3 = Wl + ((l15 < 8) ? (3 * 8 + l15) * WROWB1 : ZOFF) + lhi * 16;

  const char* Ab = Ach + w * 2048 + (lhi * 32 + l15) * 16;
  char* dbase = Ach + w * 2048;

#define ISSUE(ck, buf)                                        \
  gl_lds16(arow + (ck) * 64, dbase + (buf) * CHB);            \
  gl_lds16(arow + (ck) * 64 + 32, dbase + (buf) * CHB + 1024);

  for (int i = 1; i <= SEQ + 1; ++i) {
    const bool active = isL0 ? (i <= SEQ) : (i >= 2);
    if (active) {
      const char* Asrc = (const char*)Hcat + (size_t)((i - 1) & 1) * NBAT * HROWB;
      const char* arow = Asrc + (size_t)(32 * w + (l & 31)) * HROWB + (l >> 5) * 16;
      f16* Hw = Hcat + (size_t)(i & 1) * NBAT * 2048;

      if (isL0) {
        // -------- layer0: 0-idx step i-1, K=1024 (h0 half), 4 gate-tiles --------
        float xr[8];
#pragma unroll
        for (int mf = 0; mf < 2; ++mf)
#pragma unroll
          for (int r = 0; r < 4; ++r)
            xr[mf * 4 + r] = X[(32 * w + 16 * mf + 4 * lhi + r) * SEQ + (i - 1)];
        vm0();
        __builtin_amdgcn_sched_barrier(0);

        ISSUE(0, 0) ISSUE(1, 1) ISSUE(2, 2)
        f32x4 acc[2][4];
#pragma unroll
        for (int mf = 0; mf < 2; ++mf)
#pragma unroll
          for (int n = 0; n < 4; ++n) acc[mf][n] = f32x4{0.f, 0.f, 0.f, 0.f};

        for (int ck = 0; ck < 32; ++ck) {
          if (ck <= 29) { asm volatile("s_waitcnt vmcnt(4)" ::: "memory"); }
          else if (ck == 30) { asm volatile("s_waitcnt vmcnt(2)" ::: "memory"); }
          else { asm volatile("s_waitcnt vmcnt(0)" ::: "memory"); }
          __builtin_amdgcn_sched_barrier(0);
          const int buf = ck % 3;
          half8 a0 = *(const half8*)(Ab + buf * CHB);
          half8 a1 = *(const half8*)(Ab + buf * CHB + 256);
          half8 b0 = *(const half8*)(Wb + ck * 64);
          half8 b1 = *(const half8*)(Wb + 16 * WROWB0 + ck * 64);
          half8 b2 = *(const half8*)(Wb + 32 * WROWB0 + ck * 64);
          half8 b3 = *(const half8*)(Wb + 48 * WROWB0 + ck * 64);
          asm volatile("s_waitcnt lgkmcnt(0)" ::: "memory");
          __builtin_amdgcn_sched_barrier(0);
          if (ck < 29) { ISSUE(ck + 3, buf) }
          acc[0][0] = __builtin_amdgcn_mfma_f32_16x16x32_f16(a0, b0, acc[0][0], 0, 0, 0);
          acc[0][1] = __builtin_amdgcn_mfma_f32_16x16x32_f16(a0, b1, acc[0][1], 0, 0, 0);
          acc[0][2] = __builtin_amdgcn_mfma_f32_16x16x32_f16(a0, b2, acc[0][2], 0, 0, 0);
          acc[0][3] = __builtin_amdgcn_mfma_f32_16x16x32_f16(a0, b3, acc[0][3], 0, 0, 0);
          acc[1][0] = __builtin_amdgcn_mfma_f32_16x16x32_f16(a1, b0, acc[1][0], 0, 0, 0);
          acc[1][1] = __builtin_amdgcn_mfma_f32_16x16x32_f16(a1, b1, acc[1][1], 0, 0, 0);
          acc[1][2] = __builtin_amdgcn_mfma_f32_16x16x32_f16(a1, b2, acc[1][2], 0, 0, 0);
          acc[1][3] = __builtin_amdgcn_mfma_f32_16x16x32_f16(a1, b3, acc[1][3], 0, 0, 0);
        }

#pragma unroll
        for (int mf = 0; mf < 2; ++mf) {
#pragma unroll
          for (int r = 0; r < 4; ++r) {
            int b = 32 * w + 16 * mf + 4 * lhi + r;
            float xv = xr[mf * 4 + r];
            float gi = acc[mf][0][r] + bi + xv * wi_i;
            float gf = acc[mf][1][r] + bf + xv * wi_f;
            float gg = acc[mf][2][r] + bg + xv * wi_g;
            float go = acc[mf][3][r] + bo + xv * wi_o;
            float cn = sigm(gf) * cst[mf * 4 + r] + sigm(gi) * tanh_(gg);
            float hn = sigm(go) * tanh_(cn);
            cst[mf * 4 + r] = cn;
            Hw[(size_t)b * 2048 + j * 16 + l15] = (f16)hn;
          }
        }
      } else {
        // ---- layer1: 0-idx step i-2, K=2048 full [h0|h1] row, 4 gate-tiles ----
        //      (proven layout; N cols 8-15 are zero-padded via the zero band)
        ISSUE(0, 0) ISSUE(1, 1) ISSUE(2, 2)
        f32x4 acc[2][4];
#pragma unroll
        for (int mf = 0; mf < 2; ++mf)
#pragma unroll
          for (int n = 0; n < 4; ++n) acc[mf][n] = f32x4{0.f, 0.f, 0.f, 0.f};

        for (int ck = 0; ck < 64; ++ck) {
          if (ck <= 61) { asm volatile("s_waitcnt vmcnt(4)" ::: "memory"); }
          else if (ck == 62) { asm volatile("s_waitcnt vmcnt(2)" ::: "memory"); }
          else { asm volatile("s_waitcnt vmcnt(0)" ::: "memory"); }
          __builtin_amdgcn_sched_barrier(0);
          const int buf = ck % 3;
          half8 a0 = *(const half8*)(Ab + buf * CHB);
          half8 a1 = *(const half8*)(Ab + buf * CHB + 256);
          half8 b0 = *(const half8*)(Wg0 + ck * 64);
          half8 b1 = *(const half8*)(Wg1 + ck * 64);
          half8 b2 = *(const half8*)(Wg2 + ck * 64);
          half8 b3 = *(const half8*)(Wg3 + ck * 64);
          asm volatile("s_waitcnt lgkmcnt(0)" ::: "memory");
          __builtin_amdgcn_sched_barrier(0);
          if (ck < 61) { ISSUE(ck + 3, buf) }
          acc[0][0] = __builtin_amdgcn_mfma_f32_16x16x32_f16(a0, b0, acc[0][0], 0, 0, 0);
          acc[0][1] = __builtin_amdgcn_mfma_f32_16x16x32_f16(a0, b1, acc[0][1], 0, 0, 0);
          acc[0][2] = __builtin_amdgcn_mfma_f32_16x16x32_f16(a0, b2, acc[0][2], 0, 0, 0);
          acc[0][3] = __builtin_amdgcn_mfma_f32_16x16x32_f16(a0, b3, acc[0][3], 0, 0, 0);
          acc[1][0] = __builtin_amdgcn_mfma_f32_16x16x32_f16(a1, b0, acc[1][0], 0, 0, 0);
          acc[1][1] = __builtin_amdgcn_mfma_f32_16x16x32_f16(a1, b1, acc[1][1], 0, 0, 0);
          acc[1][2] = __builtin_amdgcn_mfma_f32_16x16x32_f16(a1, b2, acc[1][2], 0, 0, 0);
          acc[1][3] = __builtin_amdgcn_mfma_f32_16x16x32_f16(a1, b3, acc[1][3], 0, 0, 0);
        }

        // Proven epilogue shape: all four gates lane-local, no exchange.
#pragma unroll
        for (int mf = 0; mf < 2; ++mf) {
#pragma unroll
          for (int r = 0; r < 4; ++r) {
            int b = 32 * w + 16 * mf + 4 * lhi + r;
            float gi = acc[mf][0][r] + bi;
            float gf = acc[mf][1][r] + bf;
            float gg = acc[mf][2][r] + bg;
            float go = acc[mf][3][r] + bo;
            float cn = sigm(gf) * cst[mf * 4 + r] + sigm(gi) * tanh_(gg);
            float hn = sigm(go) * tanh_(cn);
            cst[mf * 4 + r] = cn;
            if (l15 < 8) Hw[(size_t)b * 2048 + 1024 + j * 8 + l15] = (f16)hn;
            float v = hn * wl;  // wl == 0 on pad lanes
            v += __shfl_xor(v, 1);
            v += __shfl_xor(v, 2);
            v += __shfl_xor(v, 4);
            v += __shfl_xor(v, 8);
            if (l15 == 0)
              yp[(size_t)(i - 2) * NBAT * NL1 + b * NL1 + j] = v;
          }
        }
      }
    }

    // ---- two-phase step barrier with per-XCD elected L2 flush ----
    // A: all stores chip-wide reach their local L2s.
    // B: one wbl2+inv(L2) per XCD, own-L1 inv per block; barB==NBLK only after
    //    every flusher finished => safe to read. (skip after last step)
    if (i <= SEQ) {
      vm0();            // this wave's stores are in the local L2
      __syncthreads();  // whole block done
      if (tid == 0) {
        __hip_atomic_fetch_add(&barA[i], 1, __ATOMIC_RELAXED, __HIP_MEMORY_SCOPE_AGENT);
        spin_until(&barA[i], NBLK);
        int who = __hip_atomic_fetch_add(&elect[i * 8 + xcd], 1, __ATOMIC_RELAXED,
                                         __HIP_MEMORY_SCOPE_AGENT);
        if (who == 0) {  // this XCD's flusher: push dirty L2 to LLC, then inv L2
          asm volatile("buffer_wbl2 sc1\n\ts_waitcnt vmcnt(0)" ::: "memory");
          asm volatile("buffer_inv sc1\n\ts_waitcnt vmcnt(0)" ::: "memory");
        }
        asm volatile("buffer_inv\n\ts_waitcnt vmcnt(0)" ::: "memory");  // own L1
        __hip_atomic_fetch_add(&barB[i], 1, __ATOMIC_RELAXED, __HIP_MEMORY_SCOPE_AGENT);
        spin_until(&barB[i], NBLK);
      }
      __syncthreads();
    }
  }
#undef ISSUE
}

__global__ __launch_bounds__(256) void zero_ws(f16* Hcat, int* barA, int* barB,
                                               int* elect) {
  int g = blockIdx.x * 256 + threadIdx.x, gs = gridDim.x * 256;
  for (int idx = g; idx < 2 * NBAT * 2048; idx += gs) Hcat[idx] = (f16)0.f;
  for (int idx = g; idx < 512; idx += gs) { barA[idx] = 0; barB[idx] = 0; }
  for (int idx = g; idx < 258 * 8; idx += gs) elect[idx] = 0;
}

__global__ __launch_bounds__(256) void final_kernel(const float* __restrict__ yp,
                                                    const float* __restrict__ blin,
                                                    float* __restrict__ out) {
  const int idx = blockIdx.x * blockDim.x + threadIdx.x;  // 0..32767
  const int t = idx >> 7, b = idx & 127;
  const float* p = yp + ((size_t)t * NBAT + b) * NL1;
  float s = 0.f;
#pragma unroll
  for (int q = 0; q < NL1; ++q) s += p[q];
  out[b * SEQ + t] = s + blin[0];
}

extern "C" void kernel_launch(void* const* d_in, const int* in_sizes, int n_in,
                              void* d_out, int out_size, void* d_ws, size_t ws_size,
                              hipStream_t stream) {
  const float* X = (const float*)d_in[0];
  const float* Wih0 = (const float*)d_in[1];
  const float* Whh0 = (const float*)d_in[2];
  const float* bih0 = (const float*)d_in[3];
  const float* bhh0 = (const float*)d_in[4];
  const float* Wih1 = (const float*)d_in[5];
  const float* Whh1 = (const float*)d_in[6];
  const float* bih1 = (const float*)d_in[7];
  const float* bhh1 = (const float*)d_in[8];
  const float* Wlin = (const float*)d_in[9];
  const float* blin = (const float*)d_in[10];
  float* out = (float*)d_out;

  char* p = (char*)d_ws;
  f16* Hcat = (f16*)p;    p += (size_t)2 * NBAT * 2048 * 2;      // 1 MB
  float* yp = (float*)p;  p += (size_t)SEQ * NBAT * NL1 * 4;     // 16.8 MB
  int* barA = (int*)p;    p += 512 * 4;
  int* barB = (int*)p;    p += 512 * 4;
  int* elect = (int*)p;   p += 258 * 8 * 4;

  hipFuncSetAttribute((const void*)lstm_persist,
                      hipFuncAttributeMaxDynamicSharedMemorySize, LDS_TOTAL);

  zero_ws<<<256, 256, 0, stream>>>(Hcat, barA, barB, elect);

  lstm_persist<<<NBLK, 256, LDS_TOTAL, stream>>>(
      X, Wih0, Whh0, bih0, bhh0, Wih1, Whh1, bih1, bhh1, Wlin,
      Hcat, yp, barA, barB, elect);

  final_kernel<<<NBAT, 256, 0, stream>>>(yp, blin, out);
}

// Round 11
// 5209.338 us; speedup vs baseline: 2.3812x; 1.4240x over previous
//
#include <hip/hip_runtime.h>
#include <stdint.h>

typedef _Float16 f16;
typedef f16 half8 __attribute__((ext_vector_type(8)));
typedef float f32x4 __attribute__((ext_vector_type(4)));

#define AS1 __attribute__((address_space(1)))
#define AS3 __attribute__((address_space(3)))

constexpr int HID = 1024;
constexpr int NBAT = 128;
constexpr int SEQ = 256;
constexpr int NL0 = 64;          // layer0 blocks: 16 units, K=1024
constexpr int NL1 = 128;         // layer1 blocks: 8 units,  K=2048 ([Wih1|Whh1])
constexpr int NBLK = NL0 + NL1;  // 192
constexpr int HROWB = 4096;      // Hcat row bytes: [h0(1024) | h1(1024)] f16
constexpr int WROWB0 = 2064;     // L0 LDS W row: 2048B + 16 pad
constexpr int WROWB1 = 4112;     // L1 LDS W row: 4096B + 16 pad
constexpr int ZOFF = 32 * WROWB1;       // 131584: start of shared zero band (L1)
constexpr int ZBYTES = 4160;            // covers ck*64 + lhi*16 (<= 4080) + slack
constexpr int WLDS = ZOFF + ZBYTES;     // 135744 >= 64*WROWB0 (132096)
constexpr int CHB = 8192;               // staged A chunk: 128 rows x 64B
constexpr int LDS_TOTAL = WLDS + 3 * CHB;  // 160320 <= 163840

// sync buffer layout (ints; 128B line separation)
constexpr int SY_INIT = 0;          // one-time init barrier
constexpr int SY_BARG = 32;         // global "XCD flushed" counter (accumulating)
constexpr int SY_CNT = 64;          // +32*x: blocks on XCD x
constexpr int SY_BARAX = 64 + 256;  // +32*x: per-XCD arrivals (accumulating)
constexpr int SY_TOTAL = 64 + 256 + 256;

__device__ __forceinline__ float sigm(float x) { return 1.0f / (1.0f + __expf(-x)); }
__device__ __forceinline__ float tanh_(float x) {
  float e = __expf(2.0f * x);
  return (e - 1.0f) / (e + 1.0f);
}
__device__ __forceinline__ void gl_lds16(const void* g, void* l) {
  __builtin_amdgcn_global_load_lds((const AS1 uint32_t*)g, (AS3 uint32_t*)l, 16, 0, 0);
}
__device__ __forceinline__ void vm0() {
  asm volatile("s_waitcnt vmcnt(0)" ::: "memory");
}
__device__ __forceinline__ void spin_until(int* p, int target) {
  uint64_t t0 = __builtin_amdgcn_s_memtime();
  while (__hip_atomic_load(p, __ATOMIC_RELAXED, __HIP_MEMORY_SCOPE_AGENT) < target) {
    __builtin_amdgcn_s_sleep(1);
    if (__builtin_amdgcn_s_memtime() - t0 > (1ULL << 29)) break;  // bounded on pathology
  }
}

__global__ __launch_bounds__(256, 1) void lstm_persist(
    const float* __restrict__ X,
    const float* __restrict__ Wih0, const float* __restrict__ Whh0,
    const float* __restrict__ bih0, const float* __restrict__ bhh0,
    const float* __restrict__ Wih1, const float* __restrict__ Whh1,
    const float* __restrict__ bih1, const float* __restrict__ bhh1,
    const float* __restrict__ Wlin,
    f16* __restrict__ Hcat,   // [2][128][2048]  ([h0|h1] per row, parity slots)
    float* __restrict__ yp,   // [256][128][128] per-L1-block y partials
    int* __restrict__ sy) {
  extern __shared__ char smem[];
  char* Wl = smem;
  char* Ach = smem + WLDS;

  const int bid = blockIdx.x, tid = threadIdx.x;
  const bool isL0 = bid < NL0;
  const int j = isL0 ? bid : bid - NL0;
  const int w = tid >> 6, l = tid & 63;
  const int l15 = l & 15, lhi = l >> 4;

  int xcd;
  asm volatile("s_getreg_b32 %0, hwreg(HW_REG_XCC_ID)" : "=s"(xcd));
  xcd &= 7;

  // ---- one-time W preload: f32 global -> f16 LDS (padded rows) ----
  if (isL0) {
    for (int it = 0; it < 256; ++it) {
      int e = it * 256 + tid;
      int r = e >> 10, k = e & 1023;                 // LDS row r = gate*16 + u
      int grow = (r >> 4) * HID + j * 16 + (r & 15);
      *(f16*)(Wl + r * WROWB0 + 2 * k) = (f16)Whh0[(size_t)grow * HID + k];
    }
  } else {
    for (int it = 0; it < 256; ++it) {
      int e = it * 256 + tid;
      int r = e >> 11, k = e & 2047;                 // LDS row r = gate*8 + u
      int grow = (r >> 3) * HID + j * 8 + (r & 7);
      float v = (k < 1024) ? Wih1[(size_t)grow * HID + k]
                           : Whh1[(size_t)grow * HID + (k - 1024)];
      *(f16*)(Wl + r * WROWB1 + 2 * k) = (f16)v;
    }
    for (int e = tid; e < ZBYTES / 2; e += 256)      // shared zero band (N-pad)
      *(f16*)(Wl + ZOFF + 2 * e) = (f16)0.f;
  }

  // ---- per-lane constants ----
  float bi, bf, bg, bo, wi_i = 0, wi_f = 0, wi_g = 0, wi_o = 0, wl = 0;
  if (isL0) {
    int m = j * 16 + l15;
    bi = bih0[m] + bhh0[m];
    bf = bih0[HID + m] + bhh0[HID + m];
    bg = bih0[2 * HID + m] + bhh0[2 * HID + m];
    bo = bih0[3 * HID + m] + bhh0[3 * HID + m];
    wi_i = Wih0[m]; wi_f = Wih0[HID + m];
    wi_g = Wih0[2 * HID + m]; wi_o = Wih0[3 * HID + m];
  } else {
    int u = j * 8 + (l15 & 7);
    bi = bih1[u] + bhh1[u];
    bf = bih1[HID + u] + bhh1[HID + u];
    bg = bih1[2 * HID + u] + bhh1[2 * HID + u];
    bo = bih1[3 * HID + u] + bhh1[3 * HID + u];
    wl = (l15 < 8) ? Wlin[u] : 0.f;  // pad lanes contribute 0 to y
  }
  float cst[8];
#pragma unroll
  for (int q = 0; q < 8; ++q) cst[q] = 0.f;

  // ---- init: learn per-XCD block count cx and XCD count nx (one-time) ----
  int cx = 0, nx = 0;
  if (tid == 0) {
    __hip_atomic_fetch_add(&sy[SY_CNT + 32 * xcd], 1, __ATOMIC_RELAXED,
                           __HIP_MEMORY_SCOPE_AGENT);
    __hip_atomic_fetch_add(&sy[SY_INIT], 1, __ATOMIC_RELAXED, __HIP_MEMORY_SCOPE_AGENT);
    spin_until(&sy[SY_INIT], NBLK);
    cx = __hip_atomic_load(&sy[SY_CNT + 32 * xcd], __ATOMIC_RELAXED,
                           __HIP_MEMORY_SCOPE_AGENT);
#pragma unroll
    for (int x = 0; x < 8; ++x)
      nx += (__hip_atomic_load(&sy[SY_CNT + 32 * x], __ATOMIC_RELAXED,
                               __HIP_MEMORY_SCOPE_AGENT) > 0);
  }
  __syncthreads();

  // L0 B pointers: proven 16-unit layout (b tiles at +16/32/48 rows)
  const char* Wb = Wl + l15 * WROWB0 + lhi * 16;
  // L1 B pointers: one per gate; cols 8-15 -> shared zero band (B-frag = 0)
  const char* Wg0 = Wl + ((l15 < 8) ? (0 * 8 + l15) * WROWB1 : ZOFF) + lhi * 16;
  const char* Wg1 = Wl + ((l15 < 8) ? (1 * 8 + l15) * WROWB1 : ZOFF) + lhi * 16;
  const char* Wg2 = Wl + ((l15 < 8) ? (2 * 8 + l15) * WROWB1 : ZOFF) + lhi * 16;
  const char* Wg3 = Wl + ((l15 < 8) ? (3 * 8 + l15) * WROWB1 : ZOFF) + lhi * 16;

  const char* Ab = Ach + w * 2048 + (lhi * 32 + l15) * 16;
  char* dbase = Ach + w * 2048;

#define ISSUE(ck, buf)                                        \
  gl_lds16(arow + (ck) * 64, dbase + (buf) * CHB);            \
  gl_lds16(arow + (ck) * 64 + 32, dbase + (buf) * CHB + 1024);

  for (int i = 1; i <= SEQ + 1; ++i) {
    const bool active = isL0 ? (i <= SEQ) : (i >= 2);
    if (active) {
      const char* Asrc = (const char*)Hcat + (size_t)((i - 1) & 1) * NBAT * HROWB;
      const char* arow = Asrc + (size_t)(32 * w + (l & 31)) * HROWB + (l >> 5) * 16;
      f16* Hw = Hcat + (size_t)(i & 1) * NBAT * 2048;

      if (isL0) {
        // -------- layer0: 0-idx step i-1, K=1024 (h0 half), 4 gate-tiles --------
        float xr[8];
#pragma unroll
        for (int mf = 0; mf < 2; ++mf)
#pragma unroll
          for (int r = 0; r < 4; ++r)
            xr[mf * 4 + r] = X[(32 * w + 16 * mf + 4 * lhi + r) * SEQ + (i - 1)];
        vm0();
        __builtin_amdgcn_sched_barrier(0);

        ISSUE(0, 0) ISSUE(1, 1) ISSUE(2, 2)
        f32x4 acc[2][4];
#pragma unroll
        for (int mf = 0; mf < 2; ++mf)
#pragma unroll
          for (int n = 0; n < 4; ++n) acc[mf][n] = f32x4{0.f, 0.f, 0.f, 0.f};

        for (int ck = 0; ck < 32; ++ck) {
          if (ck <= 29) { asm volatile("s_waitcnt vmcnt(4)" ::: "memory"); }
          else if (ck == 30) { asm volatile("s_waitcnt vmcnt(2)" ::: "memory"); }
          else { asm volatile("s_waitcnt vmcnt(0)" ::: "memory"); }
          __builtin_amdgcn_sched_barrier(0);
          const int buf = ck % 3;
          half8 a0 = *(const half8*)(Ab + buf * CHB);
          half8 a1 = *(const half8*)(Ab + buf * CHB + 256);
          half8 b0 = *(const half8*)(Wb + ck * 64);
          half8 b1 = *(const half8*)(Wb + 16 * WROWB0 + ck * 64);
          half8 b2 = *(const half8*)(Wb + 32 * WROWB0 + ck * 64);
          half8 b3 = *(const half8*)(Wb + 48 * WROWB0 + ck * 64);
          asm volatile("s_waitcnt lgkmcnt(0)" ::: "memory");
          __builtin_amdgcn_sched_barrier(0);
          if (ck < 29) { ISSUE(ck + 3, buf) }
          acc[0][0] = __builtin_amdgcn_mfma_f32_16x16x32_f16(a0, b0, acc[0][0], 0, 0, 0);
          acc[0][1] = __builtin_amdgcn_mfma_f32_16x16x32_f16(a0, b1, acc[0][1], 0, 0, 0);
          acc[0][2] = __builtin_amdgcn_mfma_f32_16x16x32_f16(a0, b2, acc[0][2], 0, 0, 0);
          acc[0][3] = __builtin_amdgcn_mfma_f32_16x16x32_f16(a0, b3, acc[0][3], 0, 0, 0);
          acc[1][0] = __builtin_amdgcn_mfma_f32_16x16x32_f16(a1, b0, acc[1][0], 0, 0, 0);
          acc[1][1] = __builtin_amdgcn_mfma_f32_16x16x32_f16(a1, b1, acc[1][1], 0, 0, 0);
          acc[1][2] = __builtin_amdgcn_mfma_f32_16x16x32_f16(a1, b2, acc[1][2], 0, 0, 0);
          acc[1][3] = __builtin_amdgcn_mfma_f32_16x16x32_f16(a1, b3, acc[1][3], 0, 0, 0);
        }

#pragma unroll
        for (int mf = 0; mf < 2; ++mf) {
#pragma unroll
          for (int r = 0; r < 4; ++r) {
            int b = 32 * w + 16 * mf + 4 * lhi + r;
            float xv = xr[mf * 4 + r];
            float gi = acc[mf][0][r] + bi + xv * wi_i;
            float gf = acc[mf][1][r] + bf + xv * wi_f;
            float gg = acc[mf][2][r] + bg + xv * wi_g;
            float go = acc[mf][3][r] + bo + xv * wi_o;
            float cn = sigm(gf) * cst[mf * 4 + r] + sigm(gi) * tanh_(gg);
            float hn = sigm(go) * tanh_(cn);
            cst[mf * 4 + r] = cn;
            Hw[(size_t)b * 2048 + j * 16 + l15] = (f16)hn;
          }
        }
      } else {
        // ---- layer1: 0-idx step i-2, K=2048 full [h0|h1] row, 4 gate-tiles ----
        //      (proven layout; N cols 8-15 are zero-padded via the zero band)
        ISSUE(0, 0) ISSUE(1, 1) ISSUE(2, 2)
        f32x4 acc[2][4];
#pragma unroll
        for (int mf = 0; mf < 2; ++mf)
#pragma unroll
          for (int n = 0; n < 4; ++n) acc[mf][n] = f32x4{0.f, 0.f, 0.f, 0.f};

        for (int ck = 0; ck < 64; ++ck) {
          if (ck <= 61) { asm volatile("s_waitcnt vmcnt(4)" ::: "memory"); }
          else if (ck == 62) { asm volatile("s_waitcnt vmcnt(2)" ::: "memory"); }
          else { asm volatile("s_waitcnt vmcnt(0)" ::: "memory"); }
          __builtin_amdgcn_sched_barrier(0);
          const int buf = ck % 3;
          half8 a0 = *(const half8*)(Ab + buf * CHB);
          half8 a1 = *(const half8*)(Ab + buf * CHB + 256);
          half8 b0 = *(const half8*)(Wg0 + ck * 64);
          half8 b1 = *(const half8*)(Wg1 + ck * 64);
          half8 b2 = *(const half8*)(Wg2 + ck * 64);
          half8 b3 = *(const half8*)(Wg3 + ck * 64);
          asm volatile("s_waitcnt lgkmcnt(0)" ::: "memory");
          __builtin_amdgcn_sched_barrier(0);
          if (ck < 61) { ISSUE(ck + 3, buf) }
          acc[0][0] = __builtin_amdgcn_mfma_f32_16x16x32_f16(a0, b0, acc[0][0], 0, 0, 0);
          acc[0][1] = __builtin_amdgcn_mfma_f32_16x16x32_f16(a0, b1, acc[0][1], 0, 0, 0);
          acc[0][2] = __builtin_amdgcn_mfma_f32_16x16x32_f16(a0, b2, acc[0][2], 0, 0, 0);
          acc[0][3] = __builtin_amdgcn_mfma_f32_16x16x32_f16(a0, b3, acc[0][3], 0, 0, 0);
          acc[1][0] = __builtin_amdgcn_mfma_f32_16x16x32_f16(a1, b0, acc[1][0], 0, 0, 0);
          acc[1][1] = __builtin_amdgcn_mfma_f32_16x16x32_f16(a1, b1, acc[1][1], 0, 0, 0);
          acc[1][2] = __builtin_amdgcn_mfma_f32_16x16x32_f16(a1, b2, acc[1][2], 0, 0, 0);
          acc[1][3] = __builtin_amdgcn_mfma_f32_16x16x32_f16(a1, b3, acc[1][3], 0, 0, 0);
        }

        // Proven epilogue shape: all four gates lane-local, no exchange.
#pragma unroll
        for (int mf = 0; mf < 2; ++mf) {
#pragma unroll
          for (int r = 0; r < 4; ++r) {
            int b = 32 * w + 16 * mf + 4 * lhi + r;
            float gi = acc[mf][0][r] + bi;
            float gf = acc[mf][1][r] + bf;
            float gg = acc[mf][2][r] + bg;
            float go = acc[mf][3][r] + bo;
            float cn = sigm(gf) * cst[mf * 4 + r] + sigm(gi) * tanh_(gg);
            float hn = sigm(go) * tanh_(cn);
            cst[mf * 4 + r] = cn;
            if (l15 < 8) Hw[(size_t)b * 2048 + 1024 + j * 8 + l15] = (f16)hn;
            float v = hn * wl;  // wl == 0 on pad lanes
            v += __shfl_xor(v, 1);
            v += __shfl_xor(v, 2);
            v += __shfl_xor(v, 4);
            v += __shfl_xor(v, 8);
            if (l15 == 0)
              yp[(size_t)(i - 2) * NBAT * NL1 + b * NL1 + j] = v;
          }
        }
      }
    }

    // ---- hierarchical step barrier (one global spin) ----
    // arrivals on per-XCD lines; last arriver per XCD = elected flusher
    // (wbl2 sc1 + inv sc1, proven R10), adds to barG; every block invs its
    // own L1, then spins once on barG == nx*i.  (skip after last step)
    if (i <= SEQ) {
      vm0();            // this wave's stores are in the local L2
      __syncthreads();  // whole block done
      if (tid == 0) {
        int old = __hip_atomic_fetch_add(&sy[SY_BARAX + 32 * xcd], 1, __ATOMIC_RELAXED,
                                         __HIP_MEMORY_SCOPE_AGENT);
        if (old == cx * i - 1) {  // last arriver on this XCD, step i
          asm volatile("buffer_wbl2 sc1\n\ts_waitcnt vmcnt(0)" ::: "memory");
          asm volatile("buffer_inv sc1\n\ts_waitcnt vmcnt(0)" ::: "memory");
          __hip_atomic_fetch_add(&sy[SY_BARG], 1, __ATOMIC_RELAXED,
                                 __HIP_MEMORY_SCOPE_AGENT);
        }
        asm volatile("buffer_inv\n\ts_waitcnt vmcnt(0)" ::: "memory");  // own L1
        spin_until(&sy[SY_BARG], nx * i);  // all XCDs flushed + arrived
      }
      __syncthreads();
    }
  }
#undef ISSUE
}

__global__ __launch_bounds__(256) void zero_ws(f16* Hcat, int* sy) {
  int g = blockIdx.x * 256 + threadIdx.x, gs = gridDim.x * 256;
  for (int idx = g; idx < 2 * NBAT * 2048; idx += gs) Hcat[idx] = (f16)0.f;
  for (int idx = g; idx < 1024; idx += gs) sy[idx] = 0;
}

__global__ __launch_bounds__(256) void final_kernel(const float* __restrict__ yp,
                                                    const float* __restrict__ blin,
                                                    float* __restrict__ out) {
  const int idx = blockIdx.x * blockDim.x + threadIdx.x;  // 0..32767
  const int t = idx >> 7, b = idx & 127;
  const float* p = yp + ((size_t)t * NBAT + b) * NL1;
  float s = 0.f;
#pragma unroll
  for (int q = 0; q < NL1; ++q) s += p[q];
  out[b * SEQ + t] = s + blin[0];
}

extern "C" void kernel_launch(void* const* d_in, const int* in_sizes, int n_in,
                              void* d_out, int out_size, void* d_ws, size_t ws_size,
                              hipStream_t stream) {
  const float* X = (const float*)d_in[0];
  const float* Wih0 = (const float*)d_in[1];
  const float* Whh0 = (const float*)d_in[2];
  const float* bih0 = (const float*)d_in[3];
  const float* bhh0 = (const float*)d_in[4];
  const float* Wih1 = (const float*)d_in[5];
  const float* Whh1 = (const float*)d_in[6];
  const float* bih1 = (const float*)d_in[7];
  const float* bhh1 = (const float*)d_in[8];
  const float* Wlin = (const float*)d_in[9];
  const float* blin = (const float*)d_in[10];
  float* out = (float*)d_out;

  char* p = (char*)d_ws;
  f16* Hcat = (f16*)p;    p += (size_t)2 * NBAT * 2048 * 2;      // 1 MB
  float* yp = (float*)p;  p += (size_t)SEQ * NBAT * NL1 * 4;     // 16.8 MB
  int* sy = (int*)p;      p += 1024 * 4;

  hipFuncSetAttribute((const void*)lstm_persist,
                      hipFuncAttributeMaxDynamicSharedMemorySize, LDS_TOTAL);

  zero_ws<<<256, 256, 0, stream>>>(Hcat, sy);

  lstm_persist<<<NBLK, 256, LDS_TOTAL, stream>>>(
      X, Wih0, Whh0, bih0, bhh0, Wih1, Whh1, bih1, bhh1, Wlin,
      Hcat, yp, sy);

  final_kernel<<<NBAT, 256, 0, stream>>>(yp, blin, out);
}

// Round 12
// 5137.827 us; speedup vs baseline: 2.4143x; 1.0139x over previous
//
#include <hip/hip_runtime.h>
#include <stdint.h>

typedef _Float16 f16;
typedef f16 half8 __attribute__((ext_vector_type(8)));
typedef float f32x4 __attribute__((ext_vector_type(4)));

constexpr int HID = 1024;
constexpr int NBAT = 128;
constexpr int SEQ = 256;
constexpr int NL0 = 64;          // layer0 blocks: 16 units, K=1024
constexpr int NL1 = 128;         // layer1 blocks: 8 units,  K=2048 ([Wih1|Whh1])
constexpr int NBLK = NL0 + NL1;  // 192
constexpr int HROWB = 4096;      // Hcat row bytes: [h0(1024) | h1(1024)] f16
constexpr int WROWB0 = 2064;     // L0 LDS W row: 2048B + 16 pad
constexpr int WROWB1 = 4112;     // L1 LDS W row: 4096B + 16 pad
constexpr int ZOFF = 32 * WROWB1;    // 131584: start of shared zero band (L1)
constexpr int ZBYTES = 4160;         // covers ck*64 + lhi*16 (<= 4080) + slack
constexpr int WLDS = ZOFF + ZBYTES;  // 135744 >= 64*WROWB0 (132096)
constexpr int LDS_TOTAL = WLDS;      // no LDS staging anymore

// sync buffer layout (ints; 128B line separation)
constexpr int SY_INIT = 0;          // one-time init barrier
constexpr int SY_BARG = 32;         // global "XCD flushed" counter (accumulating)
constexpr int SY_CNT = 64;          // +32*x: blocks on XCD x
constexpr int SY_BARAX = 64 + 256;  // +32*x: per-XCD arrivals (accumulating)

__device__ __forceinline__ float sigm(float x) { return 1.0f / (1.0f + __expf(-x)); }
__device__ __forceinline__ float tanh_(float x) {
  float e = __expf(2.0f * x);
  return (e - 1.0f) / (e + 1.0f);
}
__device__ __forceinline__ void vm0() {
  asm volatile("s_waitcnt vmcnt(0)" ::: "memory");
}
__device__ __forceinline__ void spin_until(int* p, int target) {
  uint64_t t0 = __builtin_amdgcn_s_memtime();
  while (__hip_atomic_load(p, __ATOMIC_RELAXED, __HIP_MEMORY_SCOPE_AGENT) < target) {
    __builtin_amdgcn_s_sleep(1);
    if (__builtin_amdgcn_s_memtime() - t0 > (1ULL << 29)) break;  // bounded on pathology
  }
}

__global__ __launch_bounds__(256, 1) void lstm_persist(
    const float* __restrict__ X,
    const float* __restrict__ Wih0, const float* __restrict__ Whh0,
    const float* __restrict__ bih0, const float* __restrict__ bhh0,
    const float* __restrict__ Wih1, const float* __restrict__ Whh1,
    const float* __restrict__ bih1, const float* __restrict__ bhh1,
    const float* __restrict__ Wlin,
    f16* __restrict__ Hcat,   // [2][128][2048]  ([h0|h1] per row, parity slots)
    float* __restrict__ yp,   // [256][128][128] per-L1-block y partials
    int* __restrict__ sy) {
  extern __shared__ char smem[];
  char* Wl = smem;

  const int bid = blockIdx.x, tid = threadIdx.x;
  const bool isL0 = bid < NL0;
  const int j = isL0 ? bid : bid - NL0;
  const int w = tid >> 6, l = tid & 63;
  const int l15 = l & 15, lhi = l >> 4;

  int xcd;
  asm volatile("s_getreg_b32 %0, hwreg(HW_REG_XCC_ID)" : "=s"(xcd));
  xcd &= 7;

  // ---- one-time W preload: f32 global -> f16 LDS (padded rows) ----
  if (isL0) {
    for (int it = 0; it < 256; ++it) {
      int e = it * 256 + tid;
      int r = e >> 10, k = e & 1023;                 // LDS row r = gate*16 + u
      int grow = (r >> 4) * HID + j * 16 + (r & 15);
      *(f16*)(Wl + r * WROWB0 + 2 * k) = (f16)Whh0[(size_t)grow * HID + k];
    }
  } else {
    for (int it = 0; it < 256; ++it) {
      int e = it * 256 + tid;
      int r = e >> 11, k = e & 2047;                 // LDS row r = gate*8 + u
      int grow = (r >> 3) * HID + j * 8 + (r & 7);
      float v = (k < 1024) ? Wih1[(size_t)grow * HID + k]
                           : Whh1[(size_t)grow * HID + (k - 1024)];
      *(f16*)(Wl + r * WROWB1 + 2 * k) = (f16)v;
    }
    for (int e = tid; e < ZBYTES / 2; e += 256)      // shared zero band (N-pad)
      *(f16*)(Wl + ZOFF + 2 * e) = (f16)0.f;
  }

  // ---- per-lane constants ----
  float bi, bf, bg, bo, wi_i = 0, wi_f = 0, wi_g = 0, wi_o = 0, wl = 0;
  if (isL0) {
    int m = j * 16 + l15;
    bi = bih0[m] + bhh0[m];
    bf = bih0[HID + m] + bhh0[HID + m];
    bg = bih0[2 * HID + m] + bhh0[2 * HID + m];
    bo = bih0[3 * HID + m] + bhh0[3 * HID + m];
    wi_i = Wih0[m]; wi_f = Wih0[HID + m];
    wi_g = Wih0[2 * HID + m]; wi_o = Wih0[3 * HID + m];
  } else {
    int u = j * 8 + (l15 & 7);
    bi = bih1[u] + bhh1[u];
    bf = bih1[HID + u] + bhh1[HID + u];
    bg = bih1[2 * HID + u] + bhh1[2 * HID + u];
    bo = bih1[3 * HID + u] + bhh1[3 * HID + u];
    wl = (l15 < 8) ? Wlin[u] : 0.f;  // pad lanes contribute 0 to y
  }
  float cst[8];
#pragma unroll
  for (int q = 0; q < 8; ++q) cst[q] = 0.f;

  // ---- init: learn per-XCD block count cx and XCD count nx (one-time) ----
  int cx = 0, nx = 0;
  if (tid == 0) {
    __hip_atomic_fetch_add(&sy[SY_CNT + 32 * xcd], 1, __ATOMIC_RELAXED,
                           __HIP_MEMORY_SCOPE_AGENT);
    __hip_atomic_fetch_add(&sy[SY_INIT], 1, __ATOMIC_RELAXED, __HIP_MEMORY_SCOPE_AGENT);
    spin_until(&sy[SY_INIT], NBLK);
    cx = __hip_atomic_load(&sy[SY_CNT + 32 * xcd], __ATOMIC_RELAXED,
                           __HIP_MEMORY_SCOPE_AGENT);
#pragma unroll
    for (int x = 0; x < 8; ++x)
      nx += (__hip_atomic_load(&sy[SY_CNT + 32 * x], __ATOMIC_RELAXED,
                               __HIP_MEMORY_SCOPE_AGENT) > 0);
  }
  __syncthreads();

  // L0 B pointers: proven 16-unit layout (b tiles at +16/32/48 rows)
  const char* Wb = Wl + l15 * WROWB0 + lhi * 16;
  // L1 B pointers: one per gate; cols 8-15 -> shared zero band (B-frag = 0)
  const char* Wg0 = Wl + ((l15 < 8) ? (0 * 8 + l15) * WROWB1 : ZOFF) + lhi * 16;
  const char* Wg1 = Wl + ((l15 < 8) ? (1 * 8 + l15) * WROWB1 : ZOFF) + lhi * 16;
  const char* Wg2 = Wl + ((l15 < 8) ? (2 * 8 + l15) * WROWB1 : ZOFF) + lhi * 16;
  const char* Wg3 = Wl + ((l15 < 8) ? (3 * 8 + l15) * WROWB1 : ZOFF) + lhi * 16;

  for (int i = 1; i <= SEQ + 1; ++i) {
    const bool active = isL0 ? (i <= SEQ) : (i >= 2);
    if (active) {
      const char* Asrc = (const char*)Hcat + (size_t)((i - 1) & 1) * NBAT * HROWB;
      // per-lane A-fragment pointers: one dwordx4 per chunk per m-frag
      const char* a0p = Asrc + (size_t)(32 * w + l15) * HROWB + lhi * 16;
      const char* a1p = a0p + (size_t)16 * HROWB;
      f16* Hw = Hcat + (size_t)(i & 1) * NBAT * 2048;

      if (isL0) {
        // -------- layer0: 0-idx step i-1, K=1024 (h0 half), 4 gate-tiles --------
        float xr[8];
#pragma unroll
        for (int mf = 0; mf < 2; ++mf)
#pragma unroll
          for (int r = 0; r < 4; ++r)
            xr[mf * 4 + r] = X[(32 * w + 16 * mf + 4 * lhi + r) * SEQ + (i - 1)];

        half8 pa[8], pb[8];
#pragma unroll
        for (int k0 = 0; k0 < 8; ++k0) {
          pa[k0] = *(const half8*)(a0p + k0 * 64);
          pb[k0] = *(const half8*)(a1p + k0 * 64);
        }
        f32x4 acc[2][4];
#pragma unroll
        for (int mf = 0; mf < 2; ++mf)
#pragma unroll
          for (int n = 0; n < 4; ++n) acc[mf][n] = f32x4{0.f, 0.f, 0.f, 0.f};

#pragma unroll
        for (int ck = 0; ck < 32; ++ck) {
          half8 a0 = pa[ck & 7], a1 = pb[ck & 7];
          if (ck < 24) {
            pa[ck & 7] = *(const half8*)(a0p + (ck + 8) * 64);
            pb[ck & 7] = *(const half8*)(a1p + (ck + 8) * 64);
          }
          half8 b0 = *(const half8*)(Wb + ck * 64);
          half8 b1 = *(const half8*)(Wb + 16 * WROWB0 + ck * 64);
          half8 b2 = *(const half8*)(Wb + 32 * WROWB0 + ck * 64);
          half8 b3 = *(const half8*)(Wb + 48 * WROWB0 + ck * 64);
          acc[0][0] = __builtin_amdgcn_mfma_f32_16x16x32_f16(a0, b0, acc[0][0], 0, 0, 0);
          acc[0][1] = __builtin_amdgcn_mfma_f32_16x16x32_f16(a0, b1, acc[0][1], 0, 0, 0);
          acc[0][2] = __builtin_amdgcn_mfma_f32_16x16x32_f16(a0, b2, acc[0][2], 0, 0, 0);
          acc[0][3] = __builtin_amdgcn_mfma_f32_16x16x32_f16(a0, b3, acc[0][3], 0, 0, 0);
          acc[1][0] = __builtin_amdgcn_mfma_f32_16x16x32_f16(a1, b0, acc[1][0], 0, 0, 0);
          acc[1][1] = __builtin_amdgcn_mfma_f32_16x16x32_f16(a1, b1, acc[1][1], 0, 0, 0);
          acc[1][2] = __builtin_amdgcn_mfma_f32_16x16x32_f16(a1, b2, acc[1][2], 0, 0, 0);
          acc[1][3] = __builtin_amdgcn_mfma_f32_16x16x32_f16(a1, b3, acc[1][3], 0, 0, 0);
        }

#pragma unroll
        for (int mf = 0; mf < 2; ++mf) {
#pragma unroll
          for (int r = 0; r < 4; ++r) {
            int b = 32 * w + 16 * mf + 4 * lhi + r;
            float xv = xr[mf * 4 + r];
            float gi = acc[mf][0][r] + bi + xv * wi_i;
            float gf = acc[mf][1][r] + bf + xv * wi_f;
            float gg = acc[mf][2][r] + bg + xv * wi_g;
            float go = acc[mf][3][r] + bo + xv * wi_o;
            float cn = sigm(gf) * cst[mf * 4 + r] + sigm(gi) * tanh_(gg);
            float hn = sigm(go) * tanh_(cn);
            cst[mf * 4 + r] = cn;
            Hw[(size_t)b * 2048 + j * 16 + l15] = (f16)hn;
          }
        }
      } else {
        // ---- layer1: 0-idx step i-2, K=2048 full [h0|h1] row, 4 gate-tiles ----
        half8 pa[8], pb[8];
#pragma unroll
        for (int k0 = 0; k0 < 8; ++k0) {
          pa[k0] = *(const half8*)(a0p + k0 * 64);
          pb[k0] = *(const half8*)(a1p + k0 * 64);
        }
        f32x4 acc[2][4];
#pragma unroll
        for (int mf = 0; mf < 2; ++mf)
#pragma unroll
          for (int n = 0; n < 4; ++n) acc[mf][n] = f32x4{0.f, 0.f, 0.f, 0.f};

#pragma unroll
        for (int ck = 0; ck < 64; ++ck) {
          half8 a0 = pa[ck & 7], a1 = pb[ck & 7];
          if (ck < 56) {
            pa[ck & 7] = *(const half8*)(a0p + (ck + 8) * 64);
            pb[ck & 7] = *(const half8*)(a1p + (ck + 8) * 64);
          }
          half8 b0 = *(const half8*)(Wg0 + ck * 64);
          half8 b1 = *(const half8*)(Wg1 + ck * 64);
          half8 b2 = *(const half8*)(Wg2 + ck * 64);
          half8 b3 = *(const half8*)(Wg3 + ck * 64);
          acc[0][0] = __builtin_amdgcn_mfma_f32_16x16x32_f16(a0, b0, acc[0][0], 0, 0, 0);
          acc[0][1] = __builtin_amdgcn_mfma_f32_16x16x32_f16(a0, b1, acc[0][1], 0, 0, 0);
          acc[0][2] = __builtin_amdgcn_mfma_f32_16x16x32_f16(a0, b2, acc[0][2], 0, 0, 0);
          acc[0][3] = __builtin_amdgcn_mfma_f32_16x16x32_f16(a0, b3, acc[0][3], 0, 0, 0);
          acc[1][0] = __builtin_amdgcn_mfma_f32_16x16x32_f16(a1, b0, acc[1][0], 0, 0, 0);
          acc[1][1] = __builtin_amdgcn_mfma_f32_16x16x32_f16(a1, b1, acc[1][1], 0, 0, 0);
          acc[1][2] = __builtin_amdgcn_mfma_f32_16x16x32_f16(a1, b2, acc[1][2], 0, 0, 0);
          acc[1][3] = __builtin_amdgcn_mfma_f32_16x16x32_f16(a1, b3, acc[1][3], 0, 0, 0);
        }

        // Proven epilogue shape: all four gates lane-local, no exchange.
#pragma unroll
        for (int mf = 0; mf < 2; ++mf) {
#pragma unroll
          for (int r = 0; r < 4; ++r) {
            int b = 32 * w + 16 * mf + 4 * lhi + r;
            float gi = acc[mf][0][r] + bi;
            float gf = acc[mf][1][r] + bf;
            float gg = acc[mf][2][r] + bg;
            float go = acc[mf][3][r] + bo;
            float cn = sigm(gf) * cst[mf * 4 + r] + sigm(gi) * tanh_(gg);
            float hn = sigm(go) * tanh_(cn);
            cst[mf * 4 + r] = cn;
            if (l15 < 8) Hw[(size_t)b * 2048 + 1024 + j * 8 + l15] = (f16)hn;
            float v = hn * wl;  // wl == 0 on pad lanes
            v += __shfl_xor(v, 1);
            v += __shfl_xor(v, 2);
            v += __shfl_xor(v, 4);
            v += __shfl_xor(v, 8);
            if (l15 == 0)
              yp[(size_t)(i - 2) * NBAT * NL1 + b * NL1 + j] = v;
          }
        }
      }
    }

    // ---- hierarchical step barrier (one global spin), proven in R11 ----
    if (i <= SEQ) {
      vm0();            // this wave's stores are in the local L2
      __syncthreads();  // whole block done
      if (tid == 0) {
        int old = __hip_atomic_fetch_add(&sy[SY_BARAX + 32 * xcd], 1, __ATOMIC_RELAXED,
                                         __HIP_MEMORY_SCOPE_AGENT);
        if (old == cx * i - 1) {  // last arriver on this XCD, step i
          asm volatile("buffer_wbl2 sc1\n\ts_waitcnt vmcnt(0)" ::: "memory");
          asm volatile("buffer_inv sc1\n\ts_waitcnt vmcnt(0)" ::: "memory");
          __hip_atomic_fetch_add(&sy[SY_BARG], 1, __ATOMIC_RELAXED,
                                 __HIP_MEMORY_SCOPE_AGENT);
        }
        asm volatile("buffer_inv\n\ts_waitcnt vmcnt(0)" ::: "memory");  // own L1
        spin_until(&sy[SY_BARG], nx * i);  // all XCDs flushed + arrived
      }
      __syncthreads();
    }
  }
}

__global__ __launch_bounds__(256) void zero_ws(f16* Hcat, int* sy) {
  int g = blockIdx.x * 256 + threadIdx.x, gs = gridDim.x * 256;
  for (int idx = g; idx < 2 * NBAT * 2048; idx += gs) Hcat[idx] = (f16)0.f;
  for (int idx = g; idx < 1024; idx += gs) sy[idx] = 0;
}

__global__ __launch_bounds__(256) void final_kernel(const float* __restrict__ yp,
                                                    const float* __restrict__ blin,
                                                    float* __restrict__ out) {
  const int idx = blockIdx.x * blockDim.x + threadIdx.x;  // 0..32767
  const int t = idx >> 7, b = idx & 127;
  const float* p = yp + ((size_t)t * NBAT + b) * NL1;
  float s = 0.f;
#pragma unroll
  for (int q = 0; q < NL1; ++q) s += p[q];
  out[b * SEQ + t] = s + blin[0];
}

extern "C" void kernel_launch(void* const* d_in, const int* in_sizes, int n_in,
                              void* d_out, int out_size, void* d_ws, size_t ws_size,
                              hipStream_t stream) {
  const float* X = (const float*)d_in[0];
  const float* Wih0 = (const float*)d_in[1];
  const float* Whh0 = (const float*)d_in[2];
  const float* bih0 = (const float*)d_in[3];
  const float* bhh0 = (const float*)d_in[4];
  const float* Wih1 = (const float*)d_in[5];
  const float* Whh1 = (const float*)d_in[6];
  const float* bih1 = (const float*)d_in[7];
  const float* bhh1 = (const float*)d_in[8];
  const float* Wlin = (const float*)d_in[9];
  const float* blin = (const float*)d_in[10];
  float* out = (float*)d_out;

  char* p = (char*)d_ws;
  f16* Hcat = (f16*)p;    p += (size_t)2 * NBAT * 2048 * 2;      // 1 MB
  float* yp = (float*)p;  p += (size_t)SEQ * NBAT * NL1 * 4;     // 16.8 MB
  int* sy = (int*)p;      p += 1024 * 4;

  hipFuncSetAttribute((const void*)lstm_persist,
                      hipFuncAttributeMaxDynamicSharedMemorySize, LDS_TOTAL);

  zero_ws<<<256, 256, 0, stream>>>(Hcat, sy);

  lstm_persist<<<NBLK, 256, LDS_TOTAL, stream>>>(
      X, Wih0, Whh0, bih0, bhh0, Wih1, Whh1, bih1, bhh1, Wlin,
      Hcat, yp, sy);

  final_kernel<<<NBAT, 256, 0, stream>>>(yp, blin, out);
}